// Round 2
// baseline (773.622 us; speedup 1.0000x reference)
//
#include <hip/hip_runtime.h>

// Problem constants
#define NROWS    4096
#define NBR      64
#define NODE_DIM 172
#define EDGE_DIM 172
#define TIME_DIM 100
#define OUT_DIM  272
#define KEY_DIM  444          // NODE+EDGE+TIME
#define KPAD     448          // KEY_DIM padded; row stride 896B (7*128 -> swizzle-closed)
#define QK_PAD   320          // OUT_DIM padded; row stride 640B (5*128 -> swizzle-closed)
#define N_HEADS  8
#define HEAD_DIM 34
#define KLDS_STRIDE 274       // fallback kernel only

typedef __attribute__((ext_vector_type(8))) short short8_t;  // 8 bf16 in 4 VGPRs
typedef __attribute__((ext_vector_type(4))) float f32x4;

__device__ inline short f2b(float x) {          // fp32 -> bf16 (RNE)
  unsigned u = __builtin_bit_cast(unsigned, x);
  unsigned r = (u + 0x7fffu + ((u >> 16) & 1u)) >> 16;
  return (short)r;
}
__device__ inline float b2f(short s) {
  unsigned u = ((unsigned)(unsigned short)s) << 16;
  return __builtin_bit_cast(float, u);
}

// Stage 64 rows x D fp32 (contiguous) into XOR-swizzled bf16 LDS tile, row stride KP elems.
template<int D, int KP>
__device__ inline void stage_rows(const float* __restrict__ src, int k0, char* A, int t) {
  constexpr int R4 = D / 4;
  const float4* s4 = (const float4*)src;
  for (int i = t; i < 64 * R4; i += 512) {
    float4 v = s4[i];
    int r = i / R4;
    int c = k0 + (i - r * R4) * 4;
    short4 h;
    h.x = f2b(v.x); h.y = f2b(v.y); h.z = f2b(v.z); h.w = f2b(v.w);
    *(short4*)(A + r * (2 * KP) + ((2 * c) ^ ((r & 7) << 4))) = h;
  }
}

template<int KP, int K0>
__device__ inline void pad_rows(char* A, int t) {  // zero cols K0..KP-1
  constexpr int NC = (KP - K0) / 4;
  short4 z; z.x = 0; z.y = 0; z.z = 0; z.w = 0;
  for (int i = t; i < 64 * NC; i += 512) {
    int r = i / NC;
    int c = K0 + (i - r * NC) * 4;
    *(short4*)(A + r * (2 * KP) + ((2 * c) ^ ((r & 7) << 4))) = z;
  }
}

// One 64(M) x 16(N) output stripe. B (W) from global L2, A from swizzled LDS.
template<int KP, int NKK>
__device__ inline void gemm_tile(const short* __restrict__ Wrow, const char* A,
                                 int lr, int lk, f32x4 acc[4]) {
#pragma unroll
  for (int kk = 0; kk < NKK; ++kk) {
    short8_t bfrag = *(const short8_t*)(Wrow + lr * KP + kk * 32 + lk * 8);
#pragma unroll
    for (int mt = 0; mt < 4; ++mt) {
      short8_t afrag = *(const short8_t*)(A + (mt * 16 + lr) * (2 * KP) +
                                          ((kk * 64 + lk * 16) ^ ((lr & 7) << 4)));
      acc[mt] = __builtin_amdgcn_mfma_f32_16x16x32_bf16(afrag, bfrag, acc[mt], 0, 0, 0);
    }
  }
}

// ---------------- kernel 0: weight conversion fp32 -> padded bf16 (+ per-head W_K^T) ----
__global__ void convert_w(const float* __restrict__ Wkv, const float* __restrict__ Wq,
                          const float* __restrict__ Wo, short* __restrict__ wkv_b,
                          short* __restrict__ wq_b, short* __restrict__ wo_b,
                          short* __restrict__ wkt) {
  int i = blockIdx.x * 256 + threadIdx.x;
  if (i < 544 * KPAD) {
    int r = i / KPAD, c = i - r * KPAD;
    wkv_b[i] = (c < KEY_DIM) ? f2b(Wkv[r * KEY_DIM + c]) : (short)0;
  }
  if (i < OUT_DIM * QK_PAD) {
    int r = i / QK_PAD, c = i - r * QK_PAD;
    wq_b[i] = (c < OUT_DIM) ? f2b(Wq[r * OUT_DIM + c]) : (short)0;
    wo_b[i] = (c < OUT_DIM) ? f2b(Wo[r * OUT_DIM + c]) : (short)0;
  }
  // Wkt[h][n=448][d=64] = W_KV[h*34+d][n]  (d>=34 or n>=444 -> 0)
  if (wkt && i < N_HEADS * 448 * 64) {
    int h = i / 28672;
    int rem = i - h * 28672;
    int n = rem >> 6, d = rem & 63;
    wkt[i] = (n < KEY_DIM && d < HEAD_DIM) ? f2b(Wkv[(h * HEAD_DIM + d) * KEY_DIM + n])
                                           : (short)0;
  }
}

// ---------------- kernel 1: Q = R @ W_Q^T  (64 rows per block) ----------------
__global__ __launch_bounds__(512) void q_gemm(const float* __restrict__ node_feat,
                                              const float* __restrict__ time_feat,
                                              const short* __restrict__ Wq,
                                              float* __restrict__ Qg) {
  __shared__ char Alds[64 * QK_PAD * 2];
  int rb = blockIdx.x * 64;
  int t = threadIdx.x;
  stage_rows<NODE_DIM, QK_PAD>(node_feat + (size_t)rb * NODE_DIM, 0, Alds, t);
  stage_rows<TIME_DIM, QK_PAD>(time_feat + (size_t)rb * TIME_DIM, NODE_DIM, Alds, t);
  pad_rows<QK_PAD, OUT_DIM>(Alds, t);
  __syncthreads();
  int wave = t >> 6, lane = t & 63, lr = lane & 15, lk = lane >> 4;
  f32x4 z = {0.f, 0.f, 0.f, 0.f};
  for (int nt = wave; nt < 17; nt += 8) {
    int nb = nt * 16;
    f32x4 acc[4] = {z, z, z, z};
    gemm_tile<QK_PAD, QK_PAD / 32>(Wq + nb * QK_PAD, Alds, lr, lk, acc);
#pragma unroll
    for (int mt = 0; mt < 4; ++mt)
#pragma unroll
      for (int e = 0; e < 4; ++e)
        Qg[(size_t)(rb + mt * 16 + lk * 4 + e) * OUT_DIM + nb + lr] = acc[mt][e];
  }
}

// ---------------- kernel 1b: Qt[b,h,k] = (1/sqrt(34)) sum_d Q[b,h*34+d] W_K[h*34+d,k] ----
__global__ __launch_bounds__(512) void qt_gemm(const float* __restrict__ Qg,
                                               const short* __restrict__ Wkt,
                                               short* __restrict__ Qtg) {
  __shared__ char Qp[64 * 1024];     // [row][head*128B + 2*d], d padded 34->64, swizzled
  int rb = blockIdx.x * 64, t = threadIdx.x;
  uint4 zz; zz.x = 0; zz.y = 0; zz.z = 0; zz.w = 0;
  for (int i = t; i < 4096; i += 512) ((uint4*)Qp)[i] = zz;
  __syncthreads();
  for (int i = t; i < 64 * 68; i += 512) {
    int r = i / 68, c4 = (i - r * 68) * 4;
    float4 v = *(const float4*)(Qg + (size_t)(rb + r) * OUT_DIM + c4);
    float vv[4] = {v.x, v.y, v.z, v.w};
#pragma unroll
    for (int j = 0; j < 4; ++j) {
      int c = c4 + j, h = c / HEAD_DIM, d = c - h * HEAD_DIM;
      *(short*)(Qp + r * 1024 + h * 128 + ((2 * d) ^ ((r & 7) << 4))) = f2b(vv[j]);
    }
  }
  __syncthreads();
  int wave = t >> 6, lane = t & 63, lr = lane & 15, lk = lane >> 4;
  int h = wave;                                   // one head per wave
  const short* Wh = Wkt + h * 28672;
  f32x4 z = {0.f, 0.f, 0.f, 0.f};
  for (int nt = 0; nt < 28; ++nt) {
    f32x4 acc[4] = {z, z, z, z};
#pragma unroll
    for (int kk = 0; kk < 2; ++kk) {
      short8_t bfrag = *(const short8_t*)(Wh + (nt * 16 + lr) * 64 + kk * 32 + lk * 8);
#pragma unroll
      for (int mt = 0; mt < 4; ++mt) {
        short8_t afrag = *(const short8_t*)(Qp + (mt * 16 + lr) * 1024 + h * 128 +
                                            ((kk * 64 + lk * 16) ^ ((lr & 7) << 4)));
        acc[mt] = __builtin_amdgcn_mfma_f32_16x16x32_bf16(afrag, bfrag, acc[mt], 0, 0, 0);
      }
    }
#pragma unroll
    for (int mt = 0; mt < 4; ++mt)
#pragma unroll
      for (int e = 0; e < 4; ++e)
        Qtg[(size_t)(rb + mt * 16 + lk * 4 + e) * 3584 + h * 448 + nt * 16 + lr] =
            f2b(acc[mt][e] * 0.17149858514250882f);
  }
}

// ---------------- kernel 2: fused scores(Qt.Z) + softmax + V-GEMM + P.V ----------------
__global__ __launch_bounds__(512, 4) void attn2(const float* __restrict__ nbr_node,
                                                const float* __restrict__ edge_feat,
                                                const float* __restrict__ nbr_time,
                                                const int* __restrict__ nbr_mask,
                                                const short* __restrict__ Wv,
                                                const short* __restrict__ Qtg,
                                                float* __restrict__ Og) {
  __shared__ char Alds[64 * KPAD * 2];            // 57,344 B  Z bf16 swizzled
  __shared__ char Qts[8 * KPAD * 2];              //  7,168 B  Qt bf16 swizzled rows
  __shared__ float Spart[2][64][8];               //  4,096 B
  __shared__ float P[N_HEADS * 64];               //  2,048 B     total 70,656
  int b = blockIdx.x;
  int t = threadIdx.x;

  stage_rows<NODE_DIM, KPAD>(nbr_node + (size_t)b * NBR * NODE_DIM, 0, Alds, t);
  stage_rows<EDGE_DIM, KPAD>(edge_feat + (size_t)b * NBR * EDGE_DIM, NODE_DIM, Alds, t);
  stage_rows<TIME_DIM, KPAD>(nbr_time + (size_t)b * NBR * TIME_DIM, NODE_DIM + EDGE_DIM, Alds, t);
  pad_rows<KPAD, KEY_DIM>(Alds, t);
  if (t < 448) {                                  // stage Qt[b]: 8 rows x 448 bf16
    uint4 v = ((const uint4*)(Qtg + (size_t)b * 3584))[t];
    int r = t / 56, cb = (t - r * 56) * 16;
    *(uint4*)(Qts + r * 896 + (cb ^ ((r & 7) << 4))) = v;
  }
  __syncthreads();

  int wave = t >> 6, lane = t & 63, lr = lane & 15, lk = lane >> 4;
  f32x4 z = {0.f, 0.f, 0.f, 0.f};

  // scores^T: D[h][n] = sum_k Qt[h][k] Z[n][k]; wave = (ntile 0..3, khalf 0..1)
  {
    int nt = wave & 3, kh = wave >> 2;
    f32x4 acc = z;
    const char* qbase = Qts + (lr & 7) * 896;
    const char* zbase = Alds + (nt * 16 + lr) * 896;
    int swz = (lr & 7) << 4;
#pragma unroll
    for (int k7 = 0; k7 < 7; ++k7) {
      int kb = ((kh * 7 + k7) * 64 + lk * 16) ^ swz;
      short8_t a = *(const short8_t*)(qbase + kb);
      short8_t bb = *(const short8_t*)(zbase + kb);
      acc = __builtin_amdgcn_mfma_f32_16x16x32_bf16(a, bb, acc, 0, 0, 0);
    }
#pragma unroll
    for (int e = 0; e < 4; ++e) {
      int h = lk * 4 + e;
      if (h < 8) Spart[kh][nt * 16 + lr][h] = acc[e];
    }
  }
  __syncthreads();

  // softmax: wave h, lane n  (scale folded into Qt)
  {
    int h = wave, n = lane;
    float s = Spart[0][n][h] + Spart[1][n][h];
    if (nbr_mask[(size_t)b * NBR + n] == 0) s = -1e10f;
    float m = s;
#pragma unroll
    for (int off = 32; off >= 1; off >>= 1) m = fmaxf(m, __shfl_xor(m, off));
    float e = __expf(s - m);
    float sum = e;
#pragma unroll
    for (int off = 32; off >= 1; off >>= 1) sum += __shfl_xor(sum, off);
    P[h * 64 + n] = e / sum;
  }
  __syncthreads();

  // V half: V = Z @ W_V^T with on-the-fly O = P @ V
  for (int nt = wave; nt < 17; nt += 8) {
    int vb = nt * 16;
    f32x4 acc[4] = {z, z, z, z};
    gemm_tile<KPAD, KPAD / 32>(Wv + vb * KPAD, Alds, lr, lk, acc);
    int c = vb + lr;
    const float* Ph = &P[(c / HEAD_DIM) * 64];
    float partial = 0.f;
#pragma unroll
    for (int mt = 0; mt < 4; ++mt)
#pragma unroll
      for (int e2 = 0; e2 < 4; ++e2)
        partial += Ph[mt * 16 + lk * 4 + e2] * acc[mt][e2];
    partial += __shfl_xor(partial, 16);
    partial += __shfl_xor(partial, 32);
    if (lane < 16) Og[(size_t)b * OUT_DIM + c] = partial;
  }
}

// ---------------- fallback kernel 2 (round-1, known-good): KV-GEMM + attention --------
__global__ __launch_bounds__(512) void attn_kernel(const float* __restrict__ nbr_node,
                                                   const float* __restrict__ edge_feat,
                                                   const float* __restrict__ nbr_time,
                                                   const int* __restrict__ nbr_mask,
                                                   const short* __restrict__ Wkv,
                                                   const float* __restrict__ Qg,
                                                   float* __restrict__ Og) {
  __shared__ char Alds[64 * KPAD * 2];
  __shared__ short Klds[64 * KLDS_STRIDE];
  __shared__ float Qs[OUT_DIM];
  __shared__ float P[N_HEADS * 64];
  int b = blockIdx.x;
  int t = threadIdx.x;

  stage_rows<NODE_DIM, KPAD>(nbr_node + (size_t)b * NBR * NODE_DIM, 0, Alds, t);
  stage_rows<EDGE_DIM, KPAD>(edge_feat + (size_t)b * NBR * EDGE_DIM, NODE_DIM, Alds, t);
  stage_rows<TIME_DIM, KPAD>(nbr_time + (size_t)b * NBR * TIME_DIM, NODE_DIM + EDGE_DIM, Alds, t);
  pad_rows<KPAD, KEY_DIM>(Alds, t);
  if (t < OUT_DIM) Qs[t] = Qg[(size_t)b * OUT_DIM + t];
  __syncthreads();

  int wave = t >> 6, lane = t & 63, lr = lane & 15, lk = lane >> 4;
  f32x4 z = {0.f, 0.f, 0.f, 0.f};

  for (int nt = wave; nt < 17; nt += 8) {
    int nb = nt * 16;
    f32x4 acc[4] = {z, z, z, z};
    gemm_tile<KPAD, KPAD / 32>(Wkv + nb * KPAD, Alds, lr, lk, acc);
#pragma unroll
    for (int mt = 0; mt < 4; ++mt)
#pragma unroll
      for (int e = 0; e < 4; ++e)
        Klds[(mt * 16 + lk * 4 + e) * KLDS_STRIDE + nb + lr] = f2b(acc[mt][e]);
  }
  __syncthreads();

  {
    int h = wave, n = lane;
    const short* kr = &Klds[n * KLDS_STRIDE + h * HEAD_DIM];
    const float* qh = &Qs[h * HEAD_DIM];
    float s = 0.f;
#pragma unroll
    for (int d = 0; d < HEAD_DIM; ++d) s += b2f(kr[d]) * qh[d];
    s *= 0.17149858514250882f;
    if (nbr_mask[(size_t)b * NBR + n] == 0) s = -1e10f;
    float m = s;
#pragma unroll
    for (int off = 32; off >= 1; off >>= 1) m = fmaxf(m, __shfl_xor(m, off));
    float e = __expf(s - m);
    float sum = e;
#pragma unroll
    for (int off = 32; off >= 1; off >>= 1) sum += __shfl_xor(sum, off);
    P[h * 64 + n] = e / sum;
  }
  __syncthreads();

  for (int nt = wave; nt < 17; nt += 8) {
    int vb = nt * 16;
    f32x4 acc[4] = {z, z, z, z};
    gemm_tile<KPAD, KPAD / 32>(Wkv + (OUT_DIM + vb) * KPAD, Alds, lr, lk, acc);
    int c = vb + lr;
    const float* Ph = &P[(c / HEAD_DIM) * 64];
    float partial = 0.f;
#pragma unroll
    for (int mt = 0; mt < 4; ++mt)
#pragma unroll
      for (int e2 = 0; e2 < 4; ++e2)
        partial += Ph[mt * 16 + lk * 4 + e2] * acc[mt][e2];
    partial += __shfl_xor(partial, 16);
    partial += __shfl_xor(partial, 32);
    if (lane < 16) Og[(size_t)b * OUT_DIM + c] = partial;
  }
}

// ---------------- kernel 3: out = LN(O @ W_O^T + b_O + R) ----------------
__global__ __launch_bounds__(512) void out_ln(const float* __restrict__ Og,
                                              const short* __restrict__ Wo,
                                              const float* __restrict__ bO,
                                              const float* __restrict__ node_feat,
                                              const float* __restrict__ time_feat,
                                              const float* __restrict__ gamma,
                                              const float* __restrict__ beta,
                                              float* __restrict__ out) {
  __shared__ char Alds[64 * QK_PAD * 2];
  __shared__ float X[64 * 276];
  int rb = blockIdx.x * 64;
  int t = threadIdx.x;
  stage_rows<OUT_DIM, QK_PAD>(Og + (size_t)rb * OUT_DIM, 0, Alds, t);
  pad_rows<QK_PAD, OUT_DIM>(Alds, t);
  __syncthreads();
  int wave = t >> 6, lane = t & 63, lr = lane & 15, lk = lane >> 4;
  f32x4 z = {0.f, 0.f, 0.f, 0.f};
  for (int nt = wave; nt < 17; nt += 8) {
    int nb = nt * 16;
    f32x4 acc[4] = {z, z, z, z};
    gemm_tile<QK_PAD, QK_PAD / 32>(Wo + nb * QK_PAD, Alds, lr, lk, acc);
    int c = nb + lr;
    float bo = bO[c];
#pragma unroll
    for (int mt = 0; mt < 4; ++mt)
#pragma unroll
      for (int e = 0; e < 4; ++e) {
        int r = mt * 16 + lk * 4 + e;
        int gr = rb + r;
        float Rv = (c < NODE_DIM) ? node_feat[(size_t)gr * NODE_DIM + c]
                                  : time_feat[(size_t)gr * TIME_DIM + (c - NODE_DIM)];
        X[r * 276 + c] = acc[mt][e] + bo + Rv;
      }
  }
  __syncthreads();
  int row = t >> 3, j = t & 7;
  float s1 = 0.f, s2 = 0.f;
  for (int c = j; c < OUT_DIM; c += 8) {
    float v = X[row * 276 + c];
    s1 += v; s2 += v * v;
  }
#pragma unroll
  for (int off = 4; off >= 1; off >>= 1) {
    s1 += __shfl_xor(s1, off);
    s2 += __shfl_xor(s2, off);
  }
  float mu = s1 * (1.f / OUT_DIM);
  float var = s2 * (1.f / OUT_DIM) - mu * mu;
  float inv = rsqrtf(fmaxf(var, 0.f) + 1e-5f);
  int gr = rb + row;
  for (int c = j; c < OUT_DIM; c += 8) {
    float v = X[row * 276 + c];
    out[(size_t)gr * OUT_DIM + c] = (v - mu) * inv * gamma[c] + beta[c];
  }
}

extern "C" void kernel_launch(void* const* d_in, const int* in_sizes, int n_in,
                              void* d_out, int out_size, void* d_ws, size_t ws_size,
                              hipStream_t stream) {
  const float* node_feat = (const float*)d_in[0];
  const float* time_feat = (const float*)d_in[1];
  const float* edge_feat = (const float*)d_in[2];
  const float* nbr_node  = (const float*)d_in[3];
  const float* nbr_time  = (const float*)d_in[4];
  const int*   nbr_mask  = (const int*)d_in[5];
  const float* W_Q   = (const float*)d_in[6];
  const float* W_KV  = (const float*)d_in[7];
  const float* W_O   = (const float*)d_in[8];
  const float* b_O   = (const float*)d_in[9];
  const float* gamma = (const float*)d_in[10];
  const float* beta  = (const float*)d_in[11];

  char* ws = (char*)d_ws;
  short* wkv_b = (short*)(ws);                    // 544*448*2   = 487,424
  short* wq_b  = (short*)(ws + 487424);           // 272*320*2   = 174,080
  short* wo_b  = (short*)(ws + 661504);           // 272*320*2   = 174,080
  float* Qg    = (float*)(ws + 835584);           // 4096*272*4  = 4,456,448
  float* Og    = (float*)(ws + 5292032);          // 4096*272*4  = 4,456,448 (ends 9,748,480)
  short* wkt   = (short*)(ws + 9748480);          // 8*448*64*2  = 458,752   (ends 10,207,232)
  short* Qtg   = (short*)(ws + 10207232);         // 4096*8*448*2= 29,360,128 (ends 39,567,360)
  float* out   = (float*)d_out;

  const bool big_ws = (ws_size >= 39567360ull);   // Qt path needs the full layout

  convert_w<<<(544 * KPAD + 255) / 256, 256, 0, stream>>>(
      W_KV, W_Q, W_O, wkv_b, wq_b, wo_b, big_ws ? wkt : (short*)nullptr);
  q_gemm<<<NROWS / 64, 512, 0, stream>>>(node_feat, time_feat, wq_b, Qg);
  if (big_ws) {
    qt_gemm<<<NROWS / 64, 512, 0, stream>>>(Qg, wkt, Qtg);
    attn2<<<NROWS, 512, 0, stream>>>(nbr_node, edge_feat, nbr_time, nbr_mask,
                                     wkv_b + OUT_DIM * KPAD, Qtg, Og);
  } else {
    attn_kernel<<<NROWS, 512, 0, stream>>>(nbr_node, edge_feat, nbr_time, nbr_mask,
                                           wkv_b, Qg, Og);
  }
  out_ln<<<NROWS / 64, 512, 0, stream>>>(Og, wo_b, b_O, node_feat, time_feat, gamma, beta, out);
}

// Round 3
// 388.642 us; speedup vs baseline: 1.9906x; 1.9906x over previous
//
#include <hip/hip_runtime.h>

// Problem constants
#define NROWS    4096
#define NBR      64
#define NODE_DIM 172
#define EDGE_DIM 172
#define TIME_DIM 100
#define OUT_DIM  272
#define KEY_DIM  444          // NODE+EDGE+TIME
#define KPAD     448          // KEY_DIM padded; row stride 896B (7*128 -> swizzle-closed)
#define QK_PAD   320          // OUT_DIM padded; row stride 640B (5*128 -> swizzle-closed)
#define N_HEADS  8
#define HEAD_DIM 34
#define KLDS_STRIDE 274       // fallback kernel only

typedef __attribute__((ext_vector_type(8))) short short8_t;  // 8 bf16 in 4 VGPRs
typedef __attribute__((ext_vector_type(4))) float f32x4;

__device__ inline short f2b(float x) {          // fp32 -> bf16 (RNE)
  unsigned u = __builtin_bit_cast(unsigned, x);
  unsigned r = (u + 0x7fffu + ((u >> 16) & 1u)) >> 16;
  return (short)r;
}
__device__ inline float b2f(short s) {
  unsigned u = ((unsigned)(unsigned short)s) << 16;
  return __builtin_bit_cast(float, u);
}

// Stage 64 rows x D fp32 (contiguous) into XOR-swizzled bf16 LDS tile, row stride KP elems.
template<int D, int KP>
__device__ inline void stage_rows(const float* __restrict__ src, int k0, char* A, int t) {
  constexpr int R4 = D / 4;
  const float4* s4 = (const float4*)src;
  for (int i = t; i < 64 * R4; i += 512) {
    float4 v = s4[i];
    int r = i / R4;
    int c = k0 + (i - r * R4) * 4;
    short4 h;
    h.x = f2b(v.x); h.y = f2b(v.y); h.z = f2b(v.z); h.w = f2b(v.w);
    *(short4*)(A + r * (2 * KP) + ((2 * c) ^ ((r & 7) << 4))) = h;
  }
}

template<int KP, int K0>
__device__ inline void pad_rows(char* A, int t) {  // zero cols K0..KP-1
  constexpr int NC = (KP - K0) / 4;
  short4 z; z.x = 0; z.y = 0; z.z = 0; z.w = 0;
  for (int i = t; i < 64 * NC; i += 512) {
    int r = i / NC;
    int c = K0 + (i - r * NC) * 4;
    *(short4*)(A + r * (2 * KP) + ((2 * c) ^ ((r & 7) << 4))) = z;
  }
}

// One 64(M) x 16(N) output stripe. B (W) from global L2, A from swizzled LDS.
template<int KP, int NKK>
__device__ inline void gemm_tile(const short* __restrict__ Wrow, const char* A,
                                 int lr, int lk, f32x4 acc[4]) {
#pragma unroll
  for (int kk = 0; kk < NKK; ++kk) {
    short8_t bfrag = *(const short8_t*)(Wrow + lr * KP + kk * 32 + lk * 8);
#pragma unroll
    for (int mt = 0; mt < 4; ++mt) {
      short8_t afrag = *(const short8_t*)(A + (mt * 16 + lr) * (2 * KP) +
                                          ((kk * 64 + lk * 16) ^ ((lr & 7) << 4)));
      acc[mt] = __builtin_amdgcn_mfma_f32_16x16x32_bf16(afrag, bfrag, acc[mt], 0, 0, 0);
    }
  }
}

// ---------------- kernel 0: weight conversion fp32 -> padded bf16 (+ per-head W_K^T) ----
__global__ void convert_w(const float* __restrict__ Wkv, const float* __restrict__ Wq,
                          const float* __restrict__ Wo, short* __restrict__ wkv_b,
                          short* __restrict__ wq_b, short* __restrict__ wo_b,
                          short* __restrict__ wkt) {
  int i = blockIdx.x * 256 + threadIdx.x;
  if (i < 544 * KPAD) {
    int r = i / KPAD, c = i - r * KPAD;
    wkv_b[i] = (c < KEY_DIM) ? f2b(Wkv[r * KEY_DIM + c]) : (short)0;
  }
  if (i < OUT_DIM * QK_PAD) {
    int r = i / QK_PAD, c = i - r * QK_PAD;
    wq_b[i] = (c < OUT_DIM) ? f2b(Wq[r * OUT_DIM + c]) : (short)0;
    wo_b[i] = (c < OUT_DIM) ? f2b(Wo[r * OUT_DIM + c]) : (short)0;
  }
  // Wkt[h][n=448][d=64] = W_KV[h*34+d][n]  (d>=34 or n>=444 -> 0)
  if (wkt && i < N_HEADS * 448 * 64) {
    int h = i / 28672;
    int rem = i - h * 28672;
    int n = rem >> 6, d = rem & 63;
    wkt[i] = (n < KEY_DIM && d < HEAD_DIM) ? f2b(Wkv[(h * HEAD_DIM + d) * KEY_DIM + n])
                                           : (short)0;
  }
}

// ---------------- kernel 1: Q = R @ W_Q^T  (64 rows per block) ----------------
__global__ __launch_bounds__(512) void q_gemm(const float* __restrict__ node_feat,
                                              const float* __restrict__ time_feat,
                                              const short* __restrict__ Wq,
                                              float* __restrict__ Qg) {
  __shared__ char Alds[64 * QK_PAD * 2];
  int rb = blockIdx.x * 64;
  int t = threadIdx.x;
  stage_rows<NODE_DIM, QK_PAD>(node_feat + (size_t)rb * NODE_DIM, 0, Alds, t);
  stage_rows<TIME_DIM, QK_PAD>(time_feat + (size_t)rb * TIME_DIM, NODE_DIM, Alds, t);
  pad_rows<QK_PAD, OUT_DIM>(Alds, t);
  __syncthreads();
  int wave = t >> 6, lane = t & 63, lr = lane & 15, lk = lane >> 4;
  f32x4 z = {0.f, 0.f, 0.f, 0.f};
  for (int nt = wave; nt < 17; nt += 8) {
    int nb = nt * 16;
    f32x4 acc[4] = {z, z, z, z};
    gemm_tile<QK_PAD, QK_PAD / 32>(Wq + nb * QK_PAD, Alds, lr, lk, acc);
#pragma unroll
    for (int mt = 0; mt < 4; ++mt)
#pragma unroll
      for (int e = 0; e < 4; ++e)
        Qg[(size_t)(rb + mt * 16 + lk * 4 + e) * OUT_DIM + nb + lr] = acc[mt][e];
  }
}

// ---------------- kernel 1b: Qt[b,h,k] = (1/sqrt(34)) sum_d Q[b,h*34+d] W_K[h*34+d,k] ----
__global__ __launch_bounds__(512) void qt_gemm(const float* __restrict__ Qg,
                                               const short* __restrict__ Wkt,
                                               short* __restrict__ Qtg) {
  __shared__ char Qp[64 * 1024];     // [row][head*128B + 2*d], d padded 34->64, swizzled
  int rb = blockIdx.x * 64, t = threadIdx.x;
  uint4 zz; zz.x = 0; zz.y = 0; zz.z = 0; zz.w = 0;
  for (int i = t; i < 4096; i += 512) ((uint4*)Qp)[i] = zz;
  __syncthreads();
  for (int i = t; i < 64 * 68; i += 512) {
    int r = i / 68, c4 = (i - r * 68) * 4;
    float4 v = *(const float4*)(Qg + (size_t)(rb + r) * OUT_DIM + c4);
    float vv[4] = {v.x, v.y, v.z, v.w};
#pragma unroll
    for (int j = 0; j < 4; ++j) {
      int c = c4 + j, h = c / HEAD_DIM, d = c - h * HEAD_DIM;
      *(short*)(Qp + r * 1024 + h * 128 + ((2 * d) ^ ((r & 7) << 4))) = f2b(vv[j]);
    }
  }
  __syncthreads();
  int wave = t >> 6, lane = t & 63, lr = lane & 15, lk = lane >> 4;
  int h = wave;                                   // one head per wave
  const short* Wh = Wkt + h * 28672;
  f32x4 z = {0.f, 0.f, 0.f, 0.f};
  for (int nt = 0; nt < 28; ++nt) {
    f32x4 acc[4] = {z, z, z, z};
#pragma unroll
    for (int kk = 0; kk < 2; ++kk) {
      short8_t bfrag = *(const short8_t*)(Wh + (nt * 16 + lr) * 64 + kk * 32 + lk * 8);
#pragma unroll
      for (int mt = 0; mt < 4; ++mt) {
        short8_t afrag = *(const short8_t*)(Qp + (mt * 16 + lr) * 1024 + h * 128 +
                                            ((kk * 64 + lk * 16) ^ ((lr & 7) << 4)));
        acc[mt] = __builtin_amdgcn_mfma_f32_16x16x32_bf16(afrag, bfrag, acc[mt], 0, 0, 0);
      }
    }
#pragma unroll
    for (int mt = 0; mt < 4; ++mt)
#pragma unroll
      for (int e = 0; e < 4; ++e)
        Qtg[(size_t)(rb + mt * 16 + lk * 4 + e) * 3584 + h * 448 + nt * 16 + lr] =
            f2b(acc[mt][e] * 0.17149858514250882f);
  }
}

// ---------------- kernel 2: fused scores(Qt.Z) + softmax + V-GEMM + P.V ----------------
// NOTE: plain __launch_bounds__(512) — round 2 showed that forcing min-waves=4 makes the
// compiler split the unified gfx950 reg file 64 VGPR + 64 AGPR and spill ~1 GB to scratch.
__global__ __launch_bounds__(512) void attn2(const float* __restrict__ nbr_node,
                                             const float* __restrict__ edge_feat,
                                             const float* __restrict__ nbr_time,
                                             const int* __restrict__ nbr_mask,
                                             const short* __restrict__ Wv,
                                             const short* __restrict__ Qtg,
                                             float* __restrict__ Og) {
  __shared__ char Alds[64 * KPAD * 2];            // 57,344 B  Z bf16 swizzled
  __shared__ char Qts[8 * KPAD * 2];              //  7,168 B  Qt bf16 swizzled rows
  __shared__ float Spart[2][64][8];               //  4,096 B
  __shared__ float P[N_HEADS * 64];               //  2,048 B     total 70,656
  int b = blockIdx.x;
  int t = threadIdx.x;

  stage_rows<NODE_DIM, KPAD>(nbr_node + (size_t)b * NBR * NODE_DIM, 0, Alds, t);
  stage_rows<EDGE_DIM, KPAD>(edge_feat + (size_t)b * NBR * EDGE_DIM, NODE_DIM, Alds, t);
  stage_rows<TIME_DIM, KPAD>(nbr_time + (size_t)b * NBR * TIME_DIM, NODE_DIM + EDGE_DIM, Alds, t);
  pad_rows<KPAD, KEY_DIM>(Alds, t);
  if (t < 448) {                                  // stage Qt[b]: 8 rows x 448 bf16
    uint4 v = ((const uint4*)(Qtg + (size_t)b * 3584))[t];
    int r = t / 56, cb = (t - r * 56) * 16;
    *(uint4*)(Qts + r * 896 + (cb ^ ((r & 7) << 4))) = v;
  }
  __syncthreads();

  int wave = t >> 6, lane = t & 63, lr = lane & 15, lk = lane >> 4;
  f32x4 z = {0.f, 0.f, 0.f, 0.f};

  // scores^T: D[h][n] = sum_k Qt[h][k] Z[n][k]; wave = (ntile 0..3, khalf 0..1)
  {
    int nt = wave & 3, kh = wave >> 2;
    f32x4 acc = z;
    const char* qbase = Qts + (lr & 7) * 896;
    const char* zbase = Alds + (nt * 16 + lr) * 896;
    int swz = (lr & 7) << 4;
#pragma unroll
    for (int k7 = 0; k7 < 7; ++k7) {
      int kb = ((kh * 7 + k7) * 64 + lk * 16) ^ swz;
      short8_t a = *(const short8_t*)(qbase + kb);
      short8_t bb = *(const short8_t*)(zbase + kb);
      acc = __builtin_amdgcn_mfma_f32_16x16x32_bf16(a, bb, acc, 0, 0, 0);
    }
#pragma unroll
    for (int e = 0; e < 4; ++e) {
      int h = lk * 4 + e;
      if (h < 8) Spart[kh][nt * 16 + lr][h] = acc[e];
    }
  }
  __syncthreads();

  // softmax: wave h, lane n  (scale folded into Qt)
  {
    int h = wave, n = lane;
    float s = Spart[0][n][h] + Spart[1][n][h];
    if (nbr_mask[(size_t)b * NBR + n] == 0) s = -1e10f;
    float m = s;
#pragma unroll
    for (int off = 32; off >= 1; off >>= 1) m = fmaxf(m, __shfl_xor(m, off));
    float e = __expf(s - m);
    float sum = e;
#pragma unroll
    for (int off = 32; off >= 1; off >>= 1) sum += __shfl_xor(sum, off);
    P[h * 64 + n] = e / sum;
  }
  __syncthreads();

  // V half: V = Z @ W_V^T with on-the-fly O = P @ V
  for (int nt = wave; nt < 17; nt += 8) {
    int vb = nt * 16;
    f32x4 acc[4] = {z, z, z, z};
    gemm_tile<KPAD, KPAD / 32>(Wv + vb * KPAD, Alds, lr, lk, acc);
    int c = vb + lr;
    const float* Ph = &P[(c / HEAD_DIM) * 64];
    float partial = 0.f;
#pragma unroll
    for (int mt = 0; mt < 4; ++mt)
#pragma unroll
      for (int e2 = 0; e2 < 4; ++e2)
        partial += Ph[mt * 16 + lk * 4 + e2] * acc[mt][e2];
    partial += __shfl_xor(partial, 16);
    partial += __shfl_xor(partial, 32);
    if (lane < 16) Og[(size_t)b * OUT_DIM + c] = partial;
  }
}

// ---------------- fallback kernel 2 (round-1, known-good): KV-GEMM + attention --------
__global__ __launch_bounds__(512) void attn_kernel(const float* __restrict__ nbr_node,
                                                   const float* __restrict__ edge_feat,
                                                   const float* __restrict__ nbr_time,
                                                   const int* __restrict__ nbr_mask,
                                                   const short* __restrict__ Wkv,
                                                   const float* __restrict__ Qg,
                                                   float* __restrict__ Og) {
  __shared__ char Alds[64 * KPAD * 2];
  __shared__ short Klds[64 * KLDS_STRIDE];
  __shared__ float Qs[OUT_DIM];
  __shared__ float P[N_HEADS * 64];
  int b = blockIdx.x;
  int t = threadIdx.x;

  stage_rows<NODE_DIM, KPAD>(nbr_node + (size_t)b * NBR * NODE_DIM, 0, Alds, t);
  stage_rows<EDGE_DIM, KPAD>(edge_feat + (size_t)b * NBR * EDGE_DIM, NODE_DIM, Alds, t);
  stage_rows<TIME_DIM, KPAD>(nbr_time + (size_t)b * NBR * TIME_DIM, NODE_DIM + EDGE_DIM, Alds, t);
  pad_rows<KPAD, KEY_DIM>(Alds, t);
  if (t < OUT_DIM) Qs[t] = Qg[(size_t)b * OUT_DIM + t];
  __syncthreads();

  int wave = t >> 6, lane = t & 63, lr = lane & 15, lk = lane >> 4;
  f32x4 z = {0.f, 0.f, 0.f, 0.f};

  for (int nt = wave; nt < 17; nt += 8) {
    int nb = nt * 16;
    f32x4 acc[4] = {z, z, z, z};
    gemm_tile<KPAD, KPAD / 32>(Wkv + nb * KPAD, Alds, lr, lk, acc);
#pragma unroll
    for (int mt = 0; mt < 4; ++mt)
#pragma unroll
      for (int e = 0; e < 4; ++e)
        Klds[(mt * 16 + lk * 4 + e) * KLDS_STRIDE + nb + lr] = f2b(acc[mt][e]);
  }
  __syncthreads();

  {
    int h = wave, n = lane;
    const short* kr = &Klds[n * KLDS_STRIDE + h * HEAD_DIM];
    const float* qh = &Qs[h * HEAD_DIM];
    float s = 0.f;
#pragma unroll
    for (int d = 0; d < HEAD_DIM; ++d) s += b2f(kr[d]) * qh[d];
    s *= 0.17149858514250882f;
    if (nbr_mask[(size_t)b * NBR + n] == 0) s = -1e10f;
    float m = s;
#pragma unroll
    for (int off = 32; off >= 1; off >>= 1) m = fmaxf(m, __shfl_xor(m, off));
    float e = __expf(s - m);
    float sum = e;
#pragma unroll
    for (int off = 32; off >= 1; off >>= 1) sum += __shfl_xor(sum, off);
    P[h * 64 + n] = e / sum;
  }
  __syncthreads();

  for (int nt = wave; nt < 17; nt += 8) {
    int vb = nt * 16;
    f32x4 acc[4] = {z, z, z, z};
    gemm_tile<KPAD, KPAD / 32>(Wkv + (OUT_DIM + vb) * KPAD, Alds, lr, lk, acc);
    int c = vb + lr;
    const float* Ph = &P[(c / HEAD_DIM) * 64];
    float partial = 0.f;
#pragma unroll
    for (int mt = 0; mt < 4; ++mt)
#pragma unroll
      for (int e2 = 0; e2 < 4; ++e2)
        partial += Ph[mt * 16 + lk * 4 + e2] * acc[mt][e2];
    partial += __shfl_xor(partial, 16);
    partial += __shfl_xor(partial, 32);
    if (lane < 16) Og[(size_t)b * OUT_DIM + c] = partial;
  }
}

// ---------------- kernel 3: out = LN(O @ W_O^T + b_O + R) ----------------
__global__ __launch_bounds__(512) void out_ln(const float* __restrict__ Og,
                                              const short* __restrict__ Wo,
                                              const float* __restrict__ bO,
                                              const float* __restrict__ node_feat,
                                              const float* __restrict__ time_feat,
                                              const float* __restrict__ gamma,
                                              const float* __restrict__ beta,
                                              float* __restrict__ out) {
  __shared__ char Alds[64 * QK_PAD * 2];
  __shared__ float X[64 * 276];
  int rb = blockIdx.x * 64;
  int t = threadIdx.x;
  stage_rows<OUT_DIM, QK_PAD>(Og + (size_t)rb * OUT_DIM, 0, Alds, t);
  pad_rows<QK_PAD, OUT_DIM>(Alds, t);
  __syncthreads();
  int wave = t >> 6, lane = t & 63, lr = lane & 15, lk = lane >> 4;
  f32x4 z = {0.f, 0.f, 0.f, 0.f};
  for (int nt = wave; nt < 17; nt += 8) {
    int nb = nt * 16;
    f32x4 acc[4] = {z, z, z, z};
    gemm_tile<QK_PAD, QK_PAD / 32>(Wo + nb * QK_PAD, Alds, lr, lk, acc);
    int c = nb + lr;
    float bo = bO[c];
#pragma unroll
    for (int mt = 0; mt < 4; ++mt)
#pragma unroll
      for (int e = 0; e < 4; ++e) {
        int r = mt * 16 + lk * 4 + e;
        int gr = rb + r;
        float Rv = (c < NODE_DIM) ? node_feat[(size_t)gr * NODE_DIM + c]
                                  : time_feat[(size_t)gr * TIME_DIM + (c - NODE_DIM)];
        X[r * 276 + c] = acc[mt][e] + bo + Rv;
      }
  }
  __syncthreads();
  int row = t >> 3, j = t & 7;
  float s1 = 0.f, s2 = 0.f;
  for (int c = j; c < OUT_DIM; c += 8) {
    float v = X[row * 276 + c];
    s1 += v; s2 += v * v;
  }
#pragma unroll
  for (int off = 4; off >= 1; off >>= 1) {
    s1 += __shfl_xor(s1, off);
    s2 += __shfl_xor(s2, off);
  }
  float mu = s1 * (1.f / OUT_DIM);
  float var = s2 * (1.f / OUT_DIM) - mu * mu;
  float inv = rsqrtf(fmaxf(var, 0.f) + 1e-5f);
  int gr = rb + row;
  for (int c = j; c < OUT_DIM; c += 8) {
    float v = X[row * 276 + c];
    out[(size_t)gr * OUT_DIM + c] = (v - mu) * inv * gamma[c] + beta[c];
  }
}

extern "C" void kernel_launch(void* const* d_in, const int* in_sizes, int n_in,
                              void* d_out, int out_size, void* d_ws, size_t ws_size,
                              hipStream_t stream) {
  const float* node_feat = (const float*)d_in[0];
  const float* time_feat = (const float*)d_in[1];
  const float* edge_feat = (const float*)d_in[2];
  const float* nbr_node  = (const float*)d_in[3];
  const float* nbr_time  = (const float*)d_in[4];
  const int*   nbr_mask  = (const int*)d_in[5];
  const float* W_Q   = (const float*)d_in[6];
  const float* W_KV  = (const float*)d_in[7];
  const float* W_O   = (const float*)d_in[8];
  const float* b_O   = (const float*)d_in[9];
  const float* gamma = (const float*)d_in[10];
  const float* beta  = (const float*)d_in[11];

  char* ws = (char*)d_ws;
  short* wkv_b = (short*)(ws);                    // 544*448*2   = 487,424
  short* wq_b  = (short*)(ws + 487424);           // 272*320*2   = 174,080
  short* wo_b  = (short*)(ws + 661504);           // 272*320*2   = 174,080
  float* Qg    = (float*)(ws + 835584);           // 4096*272*4  = 4,456,448
  float* Og    = (float*)(ws + 5292032);          // 4096*272*4  = 4,456,448 (ends 9,748,480)
  short* wkt   = (short*)(ws + 9748480);          // 8*448*64*2  = 458,752   (ends 10,207,232)
  short* Qtg   = (short*)(ws + 10207232);         // 4096*8*448*2= 29,360,128 (ends 39,567,360)
  float* out   = (float*)d_out;

  const bool big_ws = (ws_size >= 39567360ull);   // Qt path needs the full layout

  convert_w<<<(544 * KPAD + 255) / 256, 256, 0, stream>>>(
      W_KV, W_Q, W_O, wkv_b, wq_b, wo_b, big_ws ? wkt : (short*)nullptr);
  q_gemm<<<NROWS / 64, 512, 0, stream>>>(node_feat, time_feat, wq_b, Qg);
  if (big_ws) {
    qt_gemm<<<NROWS / 64, 512, 0, stream>>>(Qg, wkt, Qtg);
    attn2<<<NROWS, 512, 0, stream>>>(nbr_node, edge_feat, nbr_time, nbr_mask,
                                     wkv_b + OUT_DIM * KPAD, Qtg, Og);
  } else {
    attn_kernel<<<NROWS, 512, 0, stream>>>(nbr_node, edge_feat, nbr_time, nbr_mask,
                                           wkv_b, Qg, Og);
  }
  out_ln<<<NROWS / 64, 512, 0, stream>>>(Og, wo_b, b_O, node_feat, time_feat, gamma, beta, out);
}

// Round 4
// 254.216 us; speedup vs baseline: 3.0432x; 1.5288x over previous
//
#include <hip/hip_runtime.h>

// Problem constants
#define NROWS    4096
#define NBR      64
#define NODE_DIM 172
#define EDGE_DIM 172
#define TIME_DIM 100
#define OUT_DIM  272
#define KEY_DIM  444          // NODE+EDGE+TIME
#define KPAD     448          // KEY_DIM padded; row stride 896B (7*128 -> swizzle-closed)
#define QK_PAD   320          // OUT_DIM padded; row stride 640B (5*128 -> swizzle-closed)
#define N_HEADS  8
#define HEAD_DIM 34
#define KLDS_STRIDE 274       // fallback kernel only

typedef __attribute__((ext_vector_type(8))) short short8_t;  // 8 bf16 in 4 VGPRs
typedef __attribute__((ext_vector_type(4))) float f32x4;

__device__ inline short f2b(float x) {          // fp32 -> bf16 (RNE)
  unsigned u = __builtin_bit_cast(unsigned, x);
  unsigned r = (u + 0x7fffu + ((u >> 16) & 1u)) >> 16;
  return (short)r;
}
__device__ inline float b2f(short s) {
  unsigned u = ((unsigned)(unsigned short)s) << 16;
  return __builtin_bit_cast(float, u);
}

// Stage 64 rows x D fp32 (contiguous) into XOR-swizzled bf16 LDS tile, row stride KP elems.
template<int D, int KP>
__device__ inline void stage_rows(const float* __restrict__ src, int k0, char* A, int t) {
  constexpr int R4 = D / 4;
  const float4* s4 = (const float4*)src;
  for (int i = t; i < 64 * R4; i += 512) {
    float4 v = s4[i];
    int r = i / R4;
    int c = k0 + (i - r * R4) * 4;
    short4 h;
    h.x = f2b(v.x); h.y = f2b(v.y); h.z = f2b(v.z); h.w = f2b(v.w);
    *(short4*)(A + r * (2 * KP) + ((2 * c) ^ ((r & 7) << 4))) = h;
  }
}

template<int KP, int K0>
__device__ inline void pad_rows(char* A, int t) {  // zero cols K0..KP-1
  constexpr int NC = (KP - K0) / 4;
  short4 z; z.x = 0; z.y = 0; z.z = 0; z.w = 0;
  for (int i = t; i < 64 * NC; i += 512) {
    int r = i / NC;
    int c = K0 + (i - r * NC) * 4;
    *(short4*)(A + r * (2 * KP) + ((2 * c) ^ ((r & 7) << 4))) = z;
  }
}

// One 64(M) x 16(N) output stripe. B (W) from global L2, A from swizzled LDS.
template<int KP, int NKK>
__device__ inline void gemm_tile(const short* __restrict__ Wrow, const char* A,
                                 int lr, int lk, f32x4 acc[4]) {
#pragma unroll
  for (int kk = 0; kk < NKK; ++kk) {
    short8_t bfrag = *(const short8_t*)(Wrow + lr * KP + kk * 32 + lk * 8);
#pragma unroll
    for (int mt = 0; mt < 4; ++mt) {
      short8_t afrag = *(const short8_t*)(A + (mt * 16 + lr) * (2 * KP) +
                                          ((kk * 64 + lk * 16) ^ ((lr & 7) << 4)));
      acc[mt] = __builtin_amdgcn_mfma_f32_16x16x32_bf16(afrag, bfrag, acc[mt], 0, 0, 0);
    }
  }
}

// ---------------- kernel 0: weight conversion fp32 -> padded bf16 (+ W_K^T, V-head-pad) --
__global__ void convert_w(const float* __restrict__ Wkv, const float* __restrict__ Wq,
                          const float* __restrict__ Wo, short* __restrict__ wkv_b,
                          short* __restrict__ wq_b, short* __restrict__ wo_b,
                          short* __restrict__ wkt, short* __restrict__ wvh) {
  int i = blockIdx.x * 256 + threadIdx.x;
  if (i < 544 * KPAD) {
    int r = i / KPAD, c = i - r * KPAD;
    wkv_b[i] = (c < KEY_DIM) ? f2b(Wkv[r * KEY_DIM + c]) : (short)0;
  }
  if (i < OUT_DIM * QK_PAD) {
    int r = i / QK_PAD, c = i - r * QK_PAD;
    wq_b[i] = (c < OUT_DIM) ? f2b(Wq[r * OUT_DIM + c]) : (short)0;
    wo_b[i] = (c < OUT_DIM) ? f2b(Wo[r * OUT_DIM + c]) : (short)0;
  }
  // Wkt[h][n=448][d=64] = W_KV[h*34+d][n]  (d>=34 or n>=444 -> 0)
  if (wkt && i < N_HEADS * 448 * 64) {
    int h = i / 28672;
    int rem = i - h * 28672;
    int n = rem >> 6, d = rem & 63;
    wkt[i] = (n < KEY_DIM && d < HEAD_DIM) ? f2b(Wkv[(h * HEAD_DIM + d) * KEY_DIM + n])
                                           : (short)0;
  }
  // Wvh[h][c'=48][k=448] = W_KV[272 + h*34 + c'][k]  (c'>=34 or k>=444 -> 0)
  if (wvh && i < N_HEADS * 48 * 448) {
    int h = i / 21504;
    int rem = i - h * 21504;
    int cp = rem / 448, k = rem - cp * 448;
    wvh[i] = (cp < HEAD_DIM && k < KEY_DIM)
                 ? f2b(Wkv[(OUT_DIM + h * HEAD_DIM + cp) * KEY_DIM + k])
                 : (short)0;
  }
}

// ---------------- kernel 1: Q = R @ W_Q^T  (64 rows per block) ----------------
__global__ __launch_bounds__(512) void q_gemm(const float* __restrict__ node_feat,
                                              const float* __restrict__ time_feat,
                                              const short* __restrict__ Wq,
                                              float* __restrict__ Qg) {
  __shared__ char Alds[64 * QK_PAD * 2];
  int rb = blockIdx.x * 64;
  int t = threadIdx.x;
  stage_rows<NODE_DIM, QK_PAD>(node_feat + (size_t)rb * NODE_DIM, 0, Alds, t);
  stage_rows<TIME_DIM, QK_PAD>(time_feat + (size_t)rb * TIME_DIM, NODE_DIM, Alds, t);
  pad_rows<QK_PAD, OUT_DIM>(Alds, t);
  __syncthreads();
  int wave = t >> 6, lane = t & 63, lr = lane & 15, lk = lane >> 4;
  f32x4 z = {0.f, 0.f, 0.f, 0.f};
  for (int nt = wave; nt < 17; nt += 8) {
    int nb = nt * 16;
    f32x4 acc[4] = {z, z, z, z};
    gemm_tile<QK_PAD, QK_PAD / 32>(Wq + nb * QK_PAD, Alds, lr, lk, acc);
#pragma unroll
    for (int mt = 0; mt < 4; ++mt)
#pragma unroll
      for (int e = 0; e < 4; ++e)
        Qg[(size_t)(rb + mt * 16 + lk * 4 + e) * OUT_DIM + nb + lr] = acc[mt][e];
  }
}

// ---------------- kernel 1b: Qt[b,h,k] = (1/sqrt(34)) sum_d Q[b,h*34+d] W_K[h*34+d,k] ----
__global__ __launch_bounds__(512) void qt_gemm(const float* __restrict__ Qg,
                                               const short* __restrict__ Wkt,
                                               short* __restrict__ Qtg) {
  __shared__ char Qp[64 * 1024];     // [row][head*128B + 2*d], d padded 34->64, swizzled
  int rb = blockIdx.x * 64, t = threadIdx.x;
  uint4 zz; zz.x = 0; zz.y = 0; zz.z = 0; zz.w = 0;
  for (int i = t; i < 4096; i += 512) ((uint4*)Qp)[i] = zz;
  __syncthreads();
  for (int i = t; i < 64 * 68; i += 512) {
    int r = i / 68, c4 = (i - r * 68) * 4;
    float4 v = *(const float4*)(Qg + (size_t)(rb + r) * OUT_DIM + c4);
    float vv[4] = {v.x, v.y, v.z, v.w};
#pragma unroll
    for (int j = 0; j < 4; ++j) {
      int c = c4 + j, h = c / HEAD_DIM, d = c - h * HEAD_DIM;
      *(short*)(Qp + r * 1024 + h * 128 + ((2 * d) ^ ((r & 7) << 4))) = f2b(vv[j]);
    }
  }
  __syncthreads();
  int wave = t >> 6, lane = t & 63, lr = lane & 15, lk = lane >> 4;
  int h = wave;                                   // one head per wave
  const short* Wh = Wkt + h * 28672;
  f32x4 z = {0.f, 0.f, 0.f, 0.f};
  for (int nt = 0; nt < 28; ++nt) {
    f32x4 acc[4] = {z, z, z, z};
#pragma unroll
    for (int kk = 0; kk < 2; ++kk) {
      short8_t bfrag = *(const short8_t*)(Wh + (nt * 16 + lr) * 64 + kk * 32 + lk * 8);
#pragma unroll
      for (int mt = 0; mt < 4; ++mt) {
        short8_t afrag = *(const short8_t*)(Qp + (mt * 16 + lr) * 1024 + h * 128 +
                                            ((kk * 64 + lk * 16) ^ ((lr & 7) << 4)));
        acc[mt] = __builtin_amdgcn_mfma_f32_16x16x32_bf16(afrag, bfrag, acc[mt], 0, 0, 0);
      }
    }
#pragma unroll
    for (int mt = 0; mt < 4; ++mt)
#pragma unroll
      for (int e = 0; e < 4; ++e)
        Qtg[(size_t)(rb + mt * 16 + lk * 4 + e) * 3584 + h * 448 + nt * 16 + lr] =
            f2b(acc[mt][e] * 0.17149858514250882f);
  }
}

// ---------------- kernel 2 (NEW): scores + softmax + Yh = P.Z  (LDS = 63,488 B) --------
// Yh2 layout: [(h*14+kk)][b][32 bf16]  -> coalesced A-frag reads in out_ln2.
__global__ __launch_bounds__(512) void attn3(const float* __restrict__ nbr_node,
                                             const float* __restrict__ edge_feat,
                                             const float* __restrict__ nbr_time,
                                             const int* __restrict__ nbr_mask,
                                             const short* __restrict__ Qtg,
                                             short* __restrict__ Yh2) {
  __shared__ char Alds[64 * KPAD * 2];            // 57,344 B
  __shared__ float Spart[2][64][8];               //  4,096 B
  __shared__ float Pf[N_HEADS][64];               //  2,048 B   total 63,488
  int b = blockIdx.x;
  int t = threadIdx.x;

  stage_rows<NODE_DIM, KPAD>(nbr_node + (size_t)b * NBR * NODE_DIM, 0, Alds, t);
  stage_rows<EDGE_DIM, KPAD>(edge_feat + (size_t)b * NBR * EDGE_DIM, NODE_DIM, Alds, t);
  stage_rows<TIME_DIM, KPAD>(nbr_time + (size_t)b * NBR * TIME_DIM, NODE_DIM + EDGE_DIM, Alds, t);
  pad_rows<KPAD, KEY_DIM>(Alds, t);
  __syncthreads();

  int wave = t >> 6, lane = t & 63, lr = lane & 15, lk = lane >> 4;
  f32x4 z = {0.f, 0.f, 0.f, 0.f};

  // scores: D[h][n] = sum_k Qt[h][k] Z[n][k]; wave = (ntile 0..3, khalf 0..1)
  // A rows 8..15 duplicate rows 0..7 (lr&7) — they only affect discarded D rows 8..15.
  {
    int nt = wave & 3, kh = wave >> 2;
    f32x4 acc = z;
    const short* qrow = Qtg + (size_t)b * 3584 + (lr & 7) * 448;
    const char* zbase = Alds + (nt * 16 + lr) * 896;
    int swz = (lr & 7) << 4;
#pragma unroll
    for (int k7 = 0; k7 < 7; ++k7) {
      int ke = (kh * 7 + k7) * 32 + lk * 8;        // element offset in [0,448)
      short8_t a = *(const short8_t*)(qrow + ke);
      short8_t bb = *(const short8_t*)(zbase + ((2 * ke) ^ swz));
      acc = __builtin_amdgcn_mfma_f32_16x16x32_bf16(a, bb, acc, 0, 0, 0);
    }
#pragma unroll
    for (int e = 0; e < 4; ++e) {
      int h = lk * 4 + e;
      if (h < 8) Spart[kh][nt * 16 + lr][h] = acc[e];
    }
  }
  __syncthreads();

  // softmax: wave h, lane n (scale folded into Qt)
  {
    int h = wave, n = lane;
    float s = Spart[0][n][h] + Spart[1][n][h];
    if (nbr_mask[(size_t)b * NBR + n] == 0) s = -1e10f;
    float m = s;
#pragma unroll
    for (int off = 32; off >= 1; off >>= 1) m = fmaxf(m, __shfl_xor(m, off));
    float e = __expf(s - m);
    float sum = e;
#pragma unroll
    for (int off = 32; off >= 1; off >>= 1) sum += __shfl_xor(sum, off);
    Pf[h][n] = e / sum;
  }
  __syncthreads();

  // Yh[h][k] = sum_n Pf[h][n] * Z[n][k] : wave h, lane g owns 8 contiguous k.
  {
    int h = wave, g = lane;
    if (g < 56) {
      float acc[8] = {0.f, 0.f, 0.f, 0.f, 0.f, 0.f, 0.f, 0.f};
      int off0 = g * 16;                           // byte offset of k-group
#pragma unroll 4
      for (int n = 0; n < 64; ++n) {
        uint4 q = *(const uint4*)(Alds + n * 896 + (off0 ^ ((n & 7) << 4)));
        float p = Pf[h][n];
        unsigned d0 = q.x, d1 = q.y, d2 = q.z, d3 = q.w;
        acc[0] += p * __builtin_bit_cast(float, d0 << 16);
        acc[1] += p * __builtin_bit_cast(float, d0 & 0xffff0000u);
        acc[2] += p * __builtin_bit_cast(float, d1 << 16);
        acc[3] += p * __builtin_bit_cast(float, d1 & 0xffff0000u);
        acc[4] += p * __builtin_bit_cast(float, d2 << 16);
        acc[5] += p * __builtin_bit_cast(float, d2 & 0xffff0000u);
        acc[6] += p * __builtin_bit_cast(float, d3 << 16);
        acc[7] += p * __builtin_bit_cast(float, d3 & 0xffff0000u);
      }
      short8_t o;
#pragma unroll
      for (int j = 0; j < 8; ++j) o[j] = f2b(acc[j]);
      *(short8_t*)(Yh2 + ((size_t)(h * 14 + (g >> 2)) * 4096 + b) * 32 + (g & 3) * 8) = o;
    }
  }
}

// ---------------- kernel 3 (NEW): O = Yh.Wvh^T ; out = LN(O @ W_O^T + b_O + R) ---------
__global__ __launch_bounds__(512) void out_ln2(const short* __restrict__ Yh2,
                                               const short* __restrict__ Wvh,
                                               const short* __restrict__ Wo,
                                               const float* __restrict__ bO,
                                               const float* __restrict__ node_feat,
                                               const float* __restrict__ time_feat,
                                               const float* __restrict__ gamma,
                                               const float* __restrict__ beta,
                                               float* __restrict__ out) {
  __shared__ char Alds[64 * QK_PAD * 2];   // 40,960 B : O tile bf16 swizzled
  __shared__ float X[64 * 276];            // 70,656 B
  int rb = blockIdx.x * 64;
  int t = threadIdx.x;
  int wave = t >> 6, lane = t & 63, lr = lane & 15, lk = lane >> 4;
  pad_rows<QK_PAD, OUT_DIM>(Alds, t);      // zero cols 272..319 (disjoint from phase A)
  f32x4 z = {0.f, 0.f, 0.f, 0.f};

  // Phase A: O[r][h*34+cl] = sum_k Yh[r][h][k] Wvh[h][cl][k]; 24 (h,nt) pairs over 8 waves
  for (int p = wave; p < 24; p += 8) {
    int h = p / 3, nt = p - h * 3;
    f32x4 acc[4] = {z, z, z, z};
#pragma unroll
    for (int kk = 0; kk < 14; ++kk) {
      short8_t bfrag = *(const short8_t*)(Wvh + h * 21504 + (nt * 16 + lr) * 448 +
                                          kk * 32 + lk * 8);
#pragma unroll
      for (int mt = 0; mt < 4; ++mt) {
        short8_t afrag = *(const short8_t*)(
            Yh2 + ((size_t)(h * 14 + kk) * 4096 + rb + mt * 16 + lr) * 32 + lk * 8);
        acc[mt] = __builtin_amdgcn_mfma_f32_16x16x32_bf16(afrag, bfrag, acc[mt], 0, 0, 0);
      }
    }
    int cl = nt * 16 + lr;
    if (cl < HEAD_DIM) {
      int c = h * HEAD_DIM + cl;
#pragma unroll
      for (int mt = 0; mt < 4; ++mt)
#pragma unroll
        for (int e = 0; e < 4; ++e) {
          int r = mt * 16 + lk * 4 + e;
          *(short*)(Alds + r * 640 + ((2 * c) ^ ((r & 7) << 4))) = f2b(acc[mt][e]);
        }
    }
  }
  __syncthreads();

  // Phase B: proj + bias + residual into X
  for (int nt = wave; nt < 17; nt += 8) {
    int nb = nt * 16;
    f32x4 acc[4] = {z, z, z, z};
    gemm_tile<QK_PAD, QK_PAD / 32>(Wo + nb * QK_PAD, Alds, lr, lk, acc);
    int c = nb + lr;
    float bo = bO[c];
#pragma unroll
    for (int mt = 0; mt < 4; ++mt)
#pragma unroll
      for (int e = 0; e < 4; ++e) {
        int r = mt * 16 + lk * 4 + e;
        int gr = rb + r;
        float Rv = (c < NODE_DIM) ? node_feat[(size_t)gr * NODE_DIM + c]
                                  : time_feat[(size_t)gr * TIME_DIM + (c - NODE_DIM)];
        X[r * 276 + c] = acc[mt][e] + bo + Rv;
      }
  }
  __syncthreads();

  // LayerNorm
  int row = t >> 3, j = t & 7;
  float s1 = 0.f, s2 = 0.f;
  for (int c = j; c < OUT_DIM; c += 8) {
    float v = X[row * 276 + c];
    s1 += v; s2 += v * v;
  }
#pragma unroll
  for (int off = 4; off >= 1; off >>= 1) {
    s1 += __shfl_xor(s1, off);
    s2 += __shfl_xor(s2, off);
  }
  float mu = s1 * (1.f / OUT_DIM);
  float var = s2 * (1.f / OUT_DIM) - mu * mu;
  float inv = rsqrtf(fmaxf(var, 0.f) + 1e-5f);
  int gr = rb + row;
  for (int c = j; c < OUT_DIM; c += 8) {
    float v = X[row * 276 + c];
    out[(size_t)gr * OUT_DIM + c] = (v - mu) * inv * gamma[c] + beta[c];
  }
}

// ---------------- fallback kernels (round-3 path, known-good) ----------------
__global__ __launch_bounds__(512) void attn2(const float* __restrict__ nbr_node,
                                             const float* __restrict__ edge_feat,
                                             const float* __restrict__ nbr_time,
                                             const int* __restrict__ nbr_mask,
                                             const short* __restrict__ Wv,
                                             const short* __restrict__ Qtg,
                                             float* __restrict__ Og) {
  __shared__ char Alds[64 * KPAD * 2];
  __shared__ char Qts[8 * KPAD * 2];
  __shared__ float Spart[2][64][8];
  __shared__ float P[N_HEADS * 64];
  int b = blockIdx.x;
  int t = threadIdx.x;

  stage_rows<NODE_DIM, KPAD>(nbr_node + (size_t)b * NBR * NODE_DIM, 0, Alds, t);
  stage_rows<EDGE_DIM, KPAD>(edge_feat + (size_t)b * NBR * EDGE_DIM, NODE_DIM, Alds, t);
  stage_rows<TIME_DIM, KPAD>(nbr_time + (size_t)b * NBR * TIME_DIM, NODE_DIM + EDGE_DIM, Alds, t);
  pad_rows<KPAD, KEY_DIM>(Alds, t);
  if (t < 448) {
    uint4 v = ((const uint4*)(Qtg + (size_t)b * 3584))[t];
    int r = t / 56, cb = (t - r * 56) * 16;
    *(uint4*)(Qts + r * 896 + (cb ^ ((r & 7) << 4))) = v;
  }
  __syncthreads();

  int wave = t >> 6, lane = t & 63, lr = lane & 15, lk = lane >> 4;
  f32x4 z = {0.f, 0.f, 0.f, 0.f};

  {
    int nt = wave & 3, kh = wave >> 2;
    f32x4 acc = z;
    const char* qbase = Qts + (lr & 7) * 896;
    const char* zbase = Alds + (nt * 16 + lr) * 896;
    int swz = (lr & 7) << 4;
#pragma unroll
    for (int k7 = 0; k7 < 7; ++k7) {
      int kb = ((kh * 7 + k7) * 64 + lk * 16) ^ swz;
      short8_t a = *(const short8_t*)(qbase + kb);
      short8_t bb = *(const short8_t*)(zbase + kb);
      acc = __builtin_amdgcn_mfma_f32_16x16x32_bf16(a, bb, acc, 0, 0, 0);
    }
#pragma unroll
    for (int e = 0; e < 4; ++e) {
      int h = lk * 4 + e;
      if (h < 8) Spart[kh][nt * 16 + lr][h] = acc[e];
    }
  }
  __syncthreads();

  {
    int h = wave, n = lane;
    float s = Spart[0][n][h] + Spart[1][n][h];
    if (nbr_mask[(size_t)b * NBR + n] == 0) s = -1e10f;
    float m = s;
#pragma unroll
    for (int off = 32; off >= 1; off >>= 1) m = fmaxf(m, __shfl_xor(m, off));
    float e = __expf(s - m);
    float sum = e;
#pragma unroll
    for (int off = 32; off >= 1; off >>= 1) sum += __shfl_xor(sum, off);
    P[h * 64 + n] = e / sum;
  }
  __syncthreads();

  for (int nt = wave; nt < 17; nt += 8) {
    int vb = nt * 16;
    f32x4 acc[4] = {z, z, z, z};
    gemm_tile<KPAD, KPAD / 32>(Wv + vb * KPAD, Alds, lr, lk, acc);
    int c = vb + lr;
    const float* Ph = &P[(c / HEAD_DIM) * 64];
    float partial = 0.f;
#pragma unroll
    for (int mt = 0; mt < 4; ++mt)
#pragma unroll
      for (int e2 = 0; e2 < 4; ++e2)
        partial += Ph[mt * 16 + lk * 4 + e2] * acc[mt][e2];
    partial += __shfl_xor(partial, 16);
    partial += __shfl_xor(partial, 32);
    if (lane < 16) Og[(size_t)b * OUT_DIM + c] = partial;
  }
}

__global__ __launch_bounds__(512) void out_ln(const float* __restrict__ Og,
                                              const short* __restrict__ Wo,
                                              const float* __restrict__ bO,
                                              const float* __restrict__ node_feat,
                                              const float* __restrict__ time_feat,
                                              const float* __restrict__ gamma,
                                              const float* __restrict__ beta,
                                              float* __restrict__ out) {
  __shared__ char Alds[64 * QK_PAD * 2];
  __shared__ float X[64 * 276];
  int rb = blockIdx.x * 64;
  int t = threadIdx.x;
  stage_rows<OUT_DIM, QK_PAD>(Og + (size_t)rb * OUT_DIM, 0, Alds, t);
  pad_rows<QK_PAD, OUT_DIM>(Alds, t);
  __syncthreads();
  int wave = t >> 6, lane = t & 63, lr = lane & 15, lk = lane >> 4;
  f32x4 z = {0.f, 0.f, 0.f, 0.f};
  for (int nt = wave; nt < 17; nt += 8) {
    int nb = nt * 16;
    f32x4 acc[4] = {z, z, z, z};
    gemm_tile<QK_PAD, QK_PAD / 32>(Wo + nb * QK_PAD, Alds, lr, lk, acc);
    int c = nb + lr;
    float bo = bO[c];
#pragma unroll
    for (int mt = 0; mt < 4; ++mt)
#pragma unroll
      for (int e = 0; e < 4; ++e) {
        int r = mt * 16 + lk * 4 + e;
        int gr = rb + r;
        float Rv = (c < NODE_DIM) ? node_feat[(size_t)gr * NODE_DIM + c]
                                  : time_feat[(size_t)gr * TIME_DIM + (c - NODE_DIM)];
        X[r * 276 + c] = acc[mt][e] + bo + Rv;
      }
  }
  __syncthreads();
  int row = t >> 3, j = t & 7;
  float s1 = 0.f, s2 = 0.f;
  for (int c = j; c < OUT_DIM; c += 8) {
    float v = X[row * 276 + c];
    s1 += v; s2 += v * v;
  }
#pragma unroll
  for (int off = 4; off >= 1; off >>= 1) {
    s1 += __shfl_xor(s1, off);
    s2 += __shfl_xor(s2, off);
  }
  float mu = s1 * (1.f / OUT_DIM);
  float var = s2 * (1.f / OUT_DIM) - mu * mu;
  float inv = rsqrtf(fmaxf(var, 0.f) + 1e-5f);
  int gr = rb + row;
  for (int c = j; c < OUT_DIM; c += 8) {
    float v = X[row * 276 + c];
    out[(size_t)gr * OUT_DIM + c] = (v - mu) * inv * gamma[c] + beta[c];
  }
}

extern "C" void kernel_launch(void* const* d_in, const int* in_sizes, int n_in,
                              void* d_out, int out_size, void* d_ws, size_t ws_size,
                              hipStream_t stream) {
  const float* node_feat = (const float*)d_in[0];
  const float* time_feat = (const float*)d_in[1];
  const float* edge_feat = (const float*)d_in[2];
  const float* nbr_node  = (const float*)d_in[3];
  const float* nbr_time  = (const float*)d_in[4];
  const int*   nbr_mask  = (const int*)d_in[5];
  const float* W_Q   = (const float*)d_in[6];
  const float* W_KV  = (const float*)d_in[7];
  const float* W_O   = (const float*)d_in[8];
  const float* b_O   = (const float*)d_in[9];
  const float* gamma = (const float*)d_in[10];
  const float* beta  = (const float*)d_in[11];
  float* out = (float*)d_out;
  char* ws = (char*)d_ws;

  const bool huge_ws = (ws_size >= 64815104ull);  // attn3 path layout
  const bool big_ws  = (ws_size >= 39567360ull);  // round-3 attn2 path layout

  if (huge_ws) {
    short* wkv_b = (short*)(ws);                  // 487,424
    short* wq_b  = (short*)(ws + 487424);         // 174,080 -> 661,504
    short* wo_b  = (short*)(ws + 661504);         // 174,080 -> 835,584
    short* wvh   = (short*)(ws + 835584);         // 344,064 -> 1,179,648
    float* Qg    = (float*)(ws + 1179648);        // 4,456,448 -> 5,636,096
    short* wkt   = (short*)(ws + 5636096);        // 458,752 -> 6,094,848
    short* Qtg   = (short*)(ws + 6094848);        // 29,360,128 -> 35,454,976
    short* Yh2   = (short*)(ws + 35454976);       // 29,360,128 -> 64,815,104
    convert_w<<<(544 * KPAD + 255) / 256, 256, 0, stream>>>(
        W_KV, W_Q, W_O, wkv_b, wq_b, wo_b, wkt, wvh);
    q_gemm<<<NROWS / 64, 512, 0, stream>>>(node_feat, time_feat, wq_b, Qg);
    qt_gemm<<<NROWS / 64, 512, 0, stream>>>(Qg, wkt, Qtg);
    attn3<<<NROWS, 512, 0, stream>>>(nbr_node, edge_feat, nbr_time, nbr_mask, Qtg, Yh2);
    out_ln2<<<NROWS / 64, 512, 0, stream>>>(Yh2, wvh, wo_b, b_O, node_feat, time_feat,
                                            gamma, beta, out);
    return;
  }

  // fallback layouts (round-3 proven)
  short* wkv_b = (short*)(ws);
  short* wq_b  = (short*)(ws + 487424);
  short* wo_b  = (short*)(ws + 661504);
  float* Qg    = (float*)(ws + 835584);
  float* Og    = (float*)(ws + 5292032);
  short* wkt   = (short*)(ws + 9748480);
  short* Qtg   = (short*)(ws + 10207232);

  convert_w<<<(544 * KPAD + 255) / 256, 256, 0, stream>>>(
      W_KV, W_Q, W_O, wkv_b, wq_b, wo_b, big_ws ? wkt : (short*)nullptr,
      (short*)nullptr);
  q_gemm<<<NROWS / 64, 512, 0, stream>>>(node_feat, time_feat, wq_b, Qg);
  if (big_ws) {
    qt_gemm<<<NROWS / 64, 512, 0, stream>>>(Qg, wkt, Qtg);
    attn2<<<NROWS, 512, 0, stream>>>(nbr_node, edge_feat, nbr_time, nbr_mask,
                                     wkv_b + OUT_DIM * KPAD, Qtg, Og);
  } else {
    // minimal-ws path: should not happen (ws >= 39.5MB observed); reuse attn2 structures
    qt_gemm<<<NROWS / 64, 512, 0, stream>>>(Qg, wkt, Qtg);
    attn2<<<NROWS, 512, 0, stream>>>(nbr_node, edge_feat, nbr_time, nbr_mask,
                                     wkv_b + OUT_DIM * KPAD, Qtg, Og);
  }
  out_ln<<<NROWS / 64, 512, 0, stream>>>(Og, wo_b, b_O, node_feat, time_feat, gamma, beta, out);
}

// Round 5
// 245.333 us; speedup vs baseline: 3.1534x; 1.0362x over previous
//
#include <hip/hip_runtime.h>

// Problem constants
#define NROWS    4096
#define NBR      64
#define NODE_DIM 172
#define EDGE_DIM 172
#define TIME_DIM 100
#define OUT_DIM  272
#define KEY_DIM  444          // NODE+EDGE+TIME
#define KPAD     448          // KEY_DIM padded; row stride 896B (7*128 -> swizzle-closed)
#define QK_PAD   320          // OUT_DIM padded; row stride 640B (5*128 -> swizzle-closed)
#define N_HEADS  8
#define HEAD_DIM 34

typedef __attribute__((ext_vector_type(8))) short short8_t;  // 8 bf16 in 4 VGPRs
typedef __attribute__((ext_vector_type(4))) float f32x4;

__device__ inline short f2b(float x) {          // fp32 -> bf16 (RNE)
  unsigned u = __builtin_bit_cast(unsigned, x);
  unsigned r = (u + 0x7fffu + ((u >> 16) & 1u)) >> 16;
  return (short)r;
}

// Stage ROWS x D fp32 (contiguous) into XOR-swizzled bf16 LDS tile, row stride KP elems.
template<int ROWS, int D, int KP>
__device__ inline void stage_rows(const float* __restrict__ src, int k0, char* A, int t) {
  constexpr int R4 = D / 4;
  const float4* s4 = (const float4*)src;
  for (int i = t; i < ROWS * R4; i += 512) {
    float4 v = s4[i];
    int r = i / R4;
    int c = k0 + (i - r * R4) * 4;
    short4 h;
    h.x = f2b(v.x); h.y = f2b(v.y); h.z = f2b(v.z); h.w = f2b(v.w);
    *(short4*)(A + r * (2 * KP) + ((2 * c) ^ ((r & 7) << 4))) = h;
  }
}

template<int ROWS, int KP, int K0>
__device__ inline void pad_rows(char* A, int t) {  // zero cols K0..KP-1
  constexpr int NC = (KP - K0) / 4;
  short4 z; z.x = 0; z.y = 0; z.z = 0; z.w = 0;
  for (int i = t; i < ROWS * NC; i += 512) {
    int r = i / NC;
    int c = K0 + (i - r * NC) * 4;
    *(short4*)(A + r * (2 * KP) + ((2 * c) ^ ((r & 7) << 4))) = z;
  }
}

// One (MT*16)(M) x 16(N) output stripe. B (W) from global L2, A from swizzled LDS.
template<int MT, int KP, int NKK>
__device__ inline void gemm_tile(const short* __restrict__ Wrow, const char* A,
                                 int lr, int lk, f32x4* acc) {
#pragma unroll
  for (int kk = 0; kk < NKK; ++kk) {
    short8_t bfrag = *(const short8_t*)(Wrow + lr * KP + kk * 32 + lk * 8);
#pragma unroll
    for (int mt = 0; mt < MT; ++mt) {
      short8_t afrag = *(const short8_t*)(A + (mt * 16 + lr) * (2 * KP) +
                                          ((kk * 64 + lk * 16) ^ ((lr & 7) << 4)));
      acc[mt] = __builtin_amdgcn_mfma_f32_16x16x32_bf16(afrag, bfrag, acc[mt], 0, 0, 0);
    }
  }
}

// ---------------- kernel 0: weight conversion fp32 -> padded bf16 ----------------
__global__ void convert_w(const float* __restrict__ Wkv, const float* __restrict__ Wq,
                          const float* __restrict__ Wo, short* __restrict__ wq_b,
                          short* __restrict__ wo_b, short* __restrict__ wkt,
                          short* __restrict__ wvh) {
  int i = blockIdx.x * 256 + threadIdx.x;
  if (i < OUT_DIM * QK_PAD) {
    int r = i / QK_PAD, c = i - r * QK_PAD;
    wq_b[i] = (c < OUT_DIM) ? f2b(Wq[r * OUT_DIM + c]) : (short)0;
    wo_b[i] = (c < OUT_DIM) ? f2b(Wo[r * OUT_DIM + c]) : (short)0;
  }
  // Wkt[h][n=448][d=64] = W_KV[h*34+d][n]  (d>=34 or n>=444 -> 0)
  if (i < N_HEADS * 448 * 64) {
    int h = i / 28672;
    int rem = i - h * 28672;
    int n = rem >> 6, d = rem & 63;
    wkt[i] = (n < KEY_DIM && d < HEAD_DIM) ? f2b(Wkv[(h * HEAD_DIM + d) * KEY_DIM + n])
                                           : (short)0;
  }
  // Wvh[h][c'=48][k=448] = W_KV[272 + h*34 + c'][k]  (c'>=34 or k>=444 -> 0)
  if (i < N_HEADS * 48 * 448) {
    int h = i / 21504;
    int rem = i - h * 21504;
    int cp = rem / 448, k = rem - cp * 448;
    wvh[i] = (cp < HEAD_DIM && k < KEY_DIM)
                 ? f2b(Wkv[(OUT_DIM + h * HEAD_DIM + cp) * KEY_DIM + k])
                 : (short)0;
  }
}

// ---------------- kernel 1 (fused): Q = R@Wq^T (LDS) ; Qt = (1/sqrt34) Qh@Wk ----------
__global__ __launch_bounds__(512) void q_qt(const float* __restrict__ node_feat,
                                            const float* __restrict__ time_feat,
                                            const short* __restrict__ Wq,
                                            const short* __restrict__ Wkt,
                                            short* __restrict__ Qtg) {
  __shared__ char Rlds[32 * 640];    // 20,480 B : R tile bf16 swizzled
  __shared__ char Qp[32 * 1024];     // 32,768 B : Q per-head packed [row][h*128B + 2d]
  int rb = blockIdx.x * 32, t = threadIdx.x;
  stage_rows<32, NODE_DIM, QK_PAD>(node_feat + (size_t)rb * NODE_DIM, 0, Rlds, t);
  stage_rows<32, TIME_DIM, QK_PAD>(time_feat + (size_t)rb * TIME_DIM, NODE_DIM, Rlds, t);
  pad_rows<32, QK_PAD, OUT_DIM>(Rlds, t);
  {
    uint4 zz; zz.x = 0; zz.y = 0; zz.z = 0; zz.w = 0;
    for (int i = t; i < 2048; i += 512) ((uint4*)Qp)[i] = zz;
  }
  __syncthreads();
  int wave = t >> 6, lane = t & 63, lr = lane & 15, lk = lane >> 4;
  f32x4 z = {0.f, 0.f, 0.f, 0.f};

  // GEMM1: Q = R @ Wq^T, output written per-head-packed into Qp
  for (int nt = wave; nt < 17; nt += 8) {
    int nb = nt * 16;
    f32x4 acc[2] = {z, z};
    gemm_tile<2, QK_PAD, QK_PAD / 32>(Wq + nb * QK_PAD, Rlds, lr, lk, acc);
    int c = nb + lr;
    int h = c / HEAD_DIM, d = c - h * HEAD_DIM;
#pragma unroll
    for (int mt = 0; mt < 2; ++mt)
#pragma unroll
      for (int e = 0; e < 4; ++e) {
        int r = mt * 16 + lk * 4 + e;
        *(short*)(Qp + r * 1024 + h * 128 + ((2 * d) ^ ((r & 7) << 4))) = f2b(acc[mt][e]);
      }
  }
  __syncthreads();

  // GEMM2: Qt[b,h,k] = sum_d Qh[b,h,d] Wkt[h][k][d], scaled
  int h = wave;
  const short* Wh = Wkt + h * 28672;
  for (int nt = 0; nt < 28; ++nt) {
    f32x4 acc[2] = {z, z};
#pragma unroll
    for (int kk = 0; kk < 2; ++kk) {
      short8_t bfrag = *(const short8_t*)(Wh + (nt * 16 + lr) * 64 + kk * 32 + lk * 8);
#pragma unroll
      for (int mt = 0; mt < 2; ++mt) {
        short8_t afrag = *(const short8_t*)(Qp + (mt * 16 + lr) * 1024 + h * 128 +
                                            ((kk * 64 + lk * 16) ^ ((lr & 7) << 4)));
        acc[mt] = __builtin_amdgcn_mfma_f32_16x16x32_bf16(afrag, bfrag, acc[mt], 0, 0, 0);
      }
    }
#pragma unroll
    for (int mt = 0; mt < 2; ++mt)
#pragma unroll
      for (int e = 0; e < 4; ++e)
        Qtg[(size_t)(rb + mt * 16 + lk * 4 + e) * 3584 + h * 448 + nt * 16 + lr] =
            f2b(acc[mt][e] * 0.17149858514250882f);
  }
}

// ---------------- kernel 2: scores + softmax + Yh = P.Z (all-MFMA) ----------------
// Yh2 layout: [(h*14+kk2)][b][32 bf16] -> coalesced A-frag reads in out_ln2.
__global__ __launch_bounds__(512) void attn3(const float* __restrict__ nbr_node,
                                             const float* __restrict__ edge_feat,
                                             const float* __restrict__ nbr_time,
                                             const int* __restrict__ nbr_mask,
                                             const short* __restrict__ Qtg,
                                             short* __restrict__ Yh2) {
  __shared__ char Alds[64 * 896];                 // 57,344 B : Z bf16 swizzled
  __shared__ float Spart[2][64][8];               //  4,096 B
  __shared__ char Pb[16 * 128];                   //  2,048 B : P bf16 [16 rows][64 n] swz
  int b = blockIdx.x;
  int t = threadIdx.x;

  stage_rows<64, NODE_DIM, KPAD>(nbr_node + (size_t)b * NBR * NODE_DIM, 0, Alds, t);
  stage_rows<64, EDGE_DIM, KPAD>(edge_feat + (size_t)b * NBR * EDGE_DIM, NODE_DIM, Alds, t);
  stage_rows<64, TIME_DIM, KPAD>(nbr_time + (size_t)b * NBR * TIME_DIM, NODE_DIM + EDGE_DIM,
                                 Alds, t);
  pad_rows<64, KPAD, KEY_DIM>(Alds, t);
  __syncthreads();

  int wave = t >> 6, lane = t & 63, lr = lane & 15, lk = lane >> 4;
  f32x4 z = {0.f, 0.f, 0.f, 0.f};

  // scores: D[h][n] = sum_k Qt[h][k] Z[n][k]; wave = (ntile 0..3, khalf 0..1)
  {
    int nt = wave & 3, kh = wave >> 2;
    f32x4 acc = z;
    const short* qrow = Qtg + (size_t)b * 3584 + (lr & 7) * 448;
    const char* zbase = Alds + (nt * 16 + lr) * 896;
    int swz = (lr & 7) << 4;
#pragma unroll
    for (int k7 = 0; k7 < 7; ++k7) {
      int ke = (kh * 7 + k7) * 32 + lk * 8;        // element offset in [0,448)
      short8_t a = *(const short8_t*)(qrow + ke);
      short8_t bb = *(const short8_t*)(zbase + ((2 * ke) ^ swz));
      acc = __builtin_amdgcn_mfma_f32_16x16x32_bf16(a, bb, acc, 0, 0, 0);
    }
#pragma unroll
    for (int e = 0; e < 4; ++e) {
      int h = lk * 4 + e;
      if (h < 8) Spart[kh][nt * 16 + lr][h] = acc[e];
    }
  }
  __syncthreads();

  // softmax: wave h, lane n (scale folded into Qt); write P as bf16 A-tile
  {
    int h = wave, n = lane;
    float s = Spart[0][n][h] + Spart[1][n][h];
    if (nbr_mask[(size_t)b * NBR + n] == 0) s = -1e10f;
    float m = s;
#pragma unroll
    for (int off = 32; off >= 1; off >>= 1) m = fmaxf(m, __shfl_xor(m, off));
    float e = __expf(s - m);
    float sum = e;
#pragma unroll
    for (int off = 32; off >= 1; off >>= 1) sum += __shfl_xor(sum, off);
    int off2 = (2 * n) ^ ((h & 7) << 4);
    *(short*)(Pb + h * 128 + off2) = f2b(e / sum);
    *(short*)(Pb + (h + 8) * 128 + off2) = 0;     // zero pad rows 8..15
  }
  __syncthreads();

  // Yh[h][k] = sum_n P[h][n] Z[n][k] via MFMA: M=16(h-pad) N=448 K=64
  for (int vt = wave; vt < 28; vt += 8) {
    int vb = vt * 16;
    f32x4 acc = z;
#pragma unroll
    for (int kk = 0; kk < 2; ++kk) {
      short8_t pa = *(const short8_t*)(Pb + lr * 128 +
                                       ((kk * 64 + lk * 16) ^ ((lr & 7) << 4)));
      short8_t zb;
#pragma unroll
      for (int jj = 0; jj < 8; ++jj) {
        int j = (jj + lk * 2) & 7;                 // stagger banks across lk groups
        int n = kk * 32 + lk * 8 + j;
        zb[j] = *(const short*)(Alds + n * 896 + ((2 * (vb + lr)) ^ ((n & 7) << 4)));
      }
      acc = __builtin_amdgcn_mfma_f32_16x16x32_bf16(pa, zb, acc, 0, 0, 0);
    }
    if (lk < 2) {
      int k = vb + lr, kk2 = k >> 5, kp = k & 31;
#pragma unroll
      for (int e = 0; e < 4; ++e) {
        int h = lk * 4 + e;
        Yh2[((size_t)(h * 14 + kk2) * 4096 + b) * 32 + kp] = f2b(acc[e]);
      }
    }
  }
}

// ---------------- kernel 3: O = Yh.Wvh^T ; out = LN(O @ W_O^T + b_O + R) ---------
__global__ __launch_bounds__(512) void out_ln2(const short* __restrict__ Yh2,
                                               const short* __restrict__ Wvh,
                                               const short* __restrict__ Wo,
                                               const float* __restrict__ bO,
                                               const float* __restrict__ node_feat,
                                               const float* __restrict__ time_feat,
                                               const float* __restrict__ gamma,
                                               const float* __restrict__ beta,
                                               float* __restrict__ out) {
  __shared__ char Alds[32 * 640];          // 20,480 B : O tile bf16 swizzled
  __shared__ float X[32 * 276];            // 35,328 B
  int rb = blockIdx.x * 32;
  int t = threadIdx.x;
  int wave = t >> 6, lane = t & 63, lr = lane & 15, lk = lane >> 4;
  pad_rows<32, QK_PAD, OUT_DIM>(Alds, t);  // zero cols 272..319 (disjoint from phase A)
  f32x4 z = {0.f, 0.f, 0.f, 0.f};

  // Phase A: O[r][h*34+cl] = sum_k Yh[r][h][k] Wvh[h][cl][k]; 24 (h,nt) pairs / 8 waves
  for (int p = wave; p < 24; p += 8) {
    int h = p / 3, nt = p - h * 3;
    f32x4 acc[2] = {z, z};
#pragma unroll
    for (int kk = 0; kk < 14; ++kk) {
      short8_t bfrag = *(const short8_t*)(Wvh + h * 21504 + (nt * 16 + lr) * 448 +
                                          kk * 32 + lk * 8);
#pragma unroll
      for (int mt = 0; mt < 2; ++mt) {
        short8_t afrag = *(const short8_t*)(
            Yh2 + ((size_t)(h * 14 + kk) * 4096 + rb + mt * 16 + lr) * 32 + lk * 8);
        acc[mt] = __builtin_amdgcn_mfma_f32_16x16x32_bf16(afrag, bfrag, acc[mt], 0, 0, 0);
      }
    }
    int cl = nt * 16 + lr;
    if (cl < HEAD_DIM) {
      int c = h * HEAD_DIM + cl;
#pragma unroll
      for (int mt = 0; mt < 2; ++mt)
#pragma unroll
        for (int e = 0; e < 4; ++e) {
          int r = mt * 16 + lk * 4 + e;
          *(short*)(Alds + r * 640 + ((2 * c) ^ ((r & 7) << 4))) = f2b(acc[mt][e]);
        }
    }
  }
  __syncthreads();

  // Phase B: proj + bias + residual into X
  for (int nt = wave; nt < 17; nt += 8) {
    int nb = nt * 16;
    f32x4 acc[2] = {z, z};
    gemm_tile<2, QK_PAD, QK_PAD / 32>(Wo + nb * QK_PAD, Alds, lr, lk, acc);
    int c = nb + lr;
    float bo = bO[c];
#pragma unroll
    for (int mt = 0; mt < 2; ++mt)
#pragma unroll
      for (int e = 0; e < 4; ++e) {
        int r = mt * 16 + lk * 4 + e;
        int gr = rb + r;
        float Rv = (c < NODE_DIM) ? node_feat[(size_t)gr * NODE_DIM + c]
                                  : time_feat[(size_t)gr * TIME_DIM + (c - NODE_DIM)];
        X[r * 276 + c] = acc[mt][e] + bo + Rv;
      }
  }
  __syncthreads();

  // LayerNorm: 16 lanes per row
  int row = t >> 4, j = t & 15;
  float s1 = 0.f, s2 = 0.f;
  for (int c = j; c < OUT_DIM; c += 16) {
    float v = X[row * 276 + c];
    s1 += v; s2 += v * v;
  }
#pragma unroll
  for (int off = 8; off >= 1; off >>= 1) {
    s1 += __shfl_xor(s1, off);
    s2 += __shfl_xor(s2, off);
  }
  float mu = s1 * (1.f / OUT_DIM);
  float var = s2 * (1.f / OUT_DIM) - mu * mu;
  float inv = rsqrtf(fmaxf(var, 0.f) + 1e-5f);
  int gr = rb + row;
  for (int c = j; c < OUT_DIM; c += 16) {
    float v = X[row * 276 + c];
    out[(size_t)gr * OUT_DIM + c] = (v - mu) * inv * gamma[c] + beta[c];
  }
}

extern "C" void kernel_launch(void* const* d_in, const int* in_sizes, int n_in,
                              void* d_out, int out_size, void* d_ws, size_t ws_size,
                              hipStream_t stream) {
  const float* node_feat = (const float*)d_in[0];
  const float* time_feat = (const float*)d_in[1];
  const float* edge_feat = (const float*)d_in[2];
  const float* nbr_node  = (const float*)d_in[3];
  const float* nbr_time  = (const float*)d_in[4];
  const int*   nbr_mask  = (const int*)d_in[5];
  const float* W_Q   = (const float*)d_in[6];
  const float* W_KV  = (const float*)d_in[7];
  const float* W_O   = (const float*)d_in[8];
  const float* b_O   = (const float*)d_in[9];
  const float* gamma = (const float*)d_in[10];
  const float* beta  = (const float*)d_in[11];
  float* out = (float*)d_out;
  char* ws = (char*)d_ws;

  // ws layout (requires ~59.9 MB; round 4 confirmed ws >= 64.8 MB):
  short* wq_b = (short*)(ws);                     // 272*320*2   = 174,080
  short* wo_b = (short*)(ws + 174080);            // 174,080 -> 348,160
  short* wvh  = (short*)(ws + 348160);            // 8*48*448*2  = 344,064 -> 692,224
  short* wkt  = (short*)(ws + 692224);            // 8*448*64*2  = 458,752 -> 1,150,976
  short* Qtg  = (short*)(ws + 1150976);           // 4096*3584*2 = 29,360,128 -> 30,511,104
  short* Yh2  = (short*)(ws + 30511104);          // 29,360,128 -> 59,871,232

  convert_w<<<896, 256, 0, stream>>>(W_KV, W_Q, W_O, wq_b, wo_b, wkt, wvh);
  q_qt<<<NROWS / 32, 512, 0, stream>>>(node_feat, time_feat, wq_b, wkt, Qtg);
  attn3<<<NROWS, 512, 0, stream>>>(nbr_node, edge_feat, nbr_time, nbr_mask, Qtg, Yh2);
  out_ln2<<<NROWS / 32, 512, 0, stream>>>(Yh2, wvh, wo_b, b_O, node_feat, time_feat,
                                          gamma, beta, out);
}

// Round 7
// 222.032 us; speedup vs baseline: 3.4843x; 1.1049x over previous
//
#include <hip/hip_runtime.h>
#include <hip/hip_bf16.h>
#include <string.h>

// Problem constants
#define NROWS    4096
#define NBR      64
#define NODE_DIM 172
#define EDGE_DIM 172
#define TIME_DIM 100
#define OUT_DIM  272
#define KEY_DIM  444          // NODE+EDGE+TIME
#define KPAD     448          // KEY_DIM padded; row stride 896B (7*128 -> swizzle-closed)
#define QK_PAD   320          // OUT_DIM padded; row stride 640B (5*128 -> swizzle-closed)
#define N_HEADS  8
#define HEAD_DIM 34

typedef __attribute__((ext_vector_type(8))) short short8_t;  // 8 bf16 in 4 VGPRs
typedef __attribute__((ext_vector_type(4))) float f32x4;

__device__ inline short f2b(float x) {          // fp32 -> bf16 (RNE), scalar one-offs
  unsigned u = __builtin_bit_cast(unsigned, x);
  unsigned r = (u + 0x7fffu + ((u >> 16) & 1u)) >> 16;
  return (short)r;
}

__device__ inline unsigned pk2(float lo, float hi) {  // v_cvt_pk_bf16_f32 via HIP API
  __hip_bfloat162 h = __float22bfloat162_rn(make_float2(lo, hi));
  unsigned u;
  memcpy(&u, &h, 4);                              // bit-identical, reg move after opt
  return u;
}

// Stage ROWS x D fp32 (row-contiguous) into XOR-swizzled bf16 LDS tile (row stride KP elems).
// Division-free: each row handled by LPR=512/ROWS lanes; packed HW cvt; 8B LDS writes.
template<int ROWS, int D, int KP>
__device__ inline void stage_rows(const float* __restrict__ src, int k0, char* A, int t) {
  constexpr int NR4 = D / 4;                 // float4 per row
  constexpr int LPR = 512 / ROWS;            // lanes per row (8 or 16)
  int r = t / LPR;                           // pow2 -> shift
  int j = t % LPR;
  const float4* s4 = (const float4*)src + (size_t)r * NR4;
  char* Arow = A + r * (2 * KP);
  int swz = (r & 7) << 4;
  for (int f4 = j; f4 < NR4; f4 += LPR) {
    float4 v = s4[f4];
    uint2 w;
    w.x = pk2(v.x, v.y);
    w.y = pk2(v.z, v.w);
    *(uint2*)(Arow + ((2 * k0 + 8 * f4) ^ swz)) = w;
  }
}

// Zero cols K0..KP-1 ((KP-K0)*2 must be a multiple of 8).
template<int ROWS, int KP, int K0>
__device__ inline void pad_rows(char* A, int t) {
  constexpr int NC8 = (KP - K0) / 4;         // 8-byte chunks per row
  constexpr int LPR = 512 / ROWS;
  int r = t / LPR;
  int j = t % LPR;
  char* Arow = A + r * (2 * KP);
  int swz = (r & 7) << 4;
  uint2 zz; zz.x = 0; zz.y = 0;
  for (int c8 = j; c8 < NC8; c8 += LPR)
    *(uint2*)(Arow + ((2 * K0 + 8 * c8) ^ swz)) = zz;
}

// One (MT*16)(M) x 16(N) output stripe. B (W) from global L2, A from swizzled LDS.
template<int MT, int KP, int NKK>
__device__ inline void gemm_tile(const short* __restrict__ Wrow, const char* A,
                                 int lr, int lk, f32x4* acc) {
#pragma unroll
  for (int kk = 0; kk < NKK; ++kk) {
    short8_t bfrag = *(const short8_t*)(Wrow + lr * KP + kk * 32 + lk * 8);
#pragma unroll
    for (int mt = 0; mt < MT; ++mt) {
      short8_t afrag = *(const short8_t*)(A + (mt * 16 + lr) * (2 * KP) +
                                          ((kk * 64 + lk * 16) ^ ((lr & 7) << 4)));
      acc[mt] = __builtin_amdgcn_mfma_f32_16x16x32_bf16(afrag, bfrag, acc[mt], 0, 0, 0);
    }
  }
}

// ---------------- kernel 0: weight conversion fp32 -> padded bf16 ----------------
__global__ void convert_w(const float* __restrict__ Wkv, const float* __restrict__ Wq,
                          const float* __restrict__ Wo, short* __restrict__ wq_b,
                          short* __restrict__ wo_b, short* __restrict__ wkt,
                          short* __restrict__ wvh) {
  int i = blockIdx.x * 256 + threadIdx.x;
  if (i < OUT_DIM * QK_PAD) {
    int r = i / QK_PAD, c = i - r * QK_PAD;
    wq_b[i] = (c < OUT_DIM) ? f2b(Wq[r * OUT_DIM + c]) : (short)0;
    wo_b[i] = (c < OUT_DIM) ? f2b(Wo[r * OUT_DIM + c]) : (short)0;
  }
  // Wkt[h][n=448][d=64] = W_KV[h*34+d][n]  (d>=34 or n>=444 -> 0)
  if (i < N_HEADS * 448 * 64) {
    int h = i / 28672;
    int rem = i - h * 28672;
    int n = rem >> 6, d = rem & 63;
    wkt[i] = (n < KEY_DIM && d < HEAD_DIM) ? f2b(Wkv[(h * HEAD_DIM + d) * KEY_DIM + n])
                                           : (short)0;
  }
  // Wvh[h][c'=48][k=448] = W_KV[272 + h*34 + c'][k]  (c'>=34 or k>=444 -> 0)
  if (i < N_HEADS * 48 * 448) {
    int h = i / 21504;
    int rem = i - h * 21504;
    int cp = rem / 448, k = rem - cp * 448;
    wvh[i] = (cp < HEAD_DIM && k < KEY_DIM)
                 ? f2b(Wkv[(OUT_DIM + h * HEAD_DIM + cp) * KEY_DIM + k])
                 : (short)0;
  }
}

// ---------------- kernel 1 (fused): Q = R@Wq^T (LDS) ; Qt = (1/sqrt34) Qh@Wk ----------
__global__ __launch_bounds__(512) void q_qt(const float* __restrict__ node_feat,
                                            const float* __restrict__ time_feat,
                                            const short* __restrict__ Wq,
                                            const short* __restrict__ Wkt,
                                            short* __restrict__ Qtg) {
  __shared__ char Rlds[32 * 640];    // 20,480 B : R tile bf16 swizzled
  __shared__ char Qp[32 * 1024];     // 32,768 B : Q per-head packed [row][h*128B + 2d]
  int rb = blockIdx.x * 32, t = threadIdx.x;
  stage_rows<32, NODE_DIM, QK_PAD>(node_feat + (size_t)rb * NODE_DIM, 0, Rlds, t);
  stage_rows<32, TIME_DIM, QK_PAD>(time_feat + (size_t)rb * TIME_DIM, NODE_DIM, Rlds, t);
  pad_rows<32, QK_PAD, OUT_DIM>(Rlds, t);
  {
    uint4 zz; zz.x = 0; zz.y = 0; zz.z = 0; zz.w = 0;
    for (int i = t; i < 2048; i += 512) ((uint4*)Qp)[i] = zz;
  }
  __syncthreads();
  int wave = t >> 6, lane = t & 63, lr = lane & 15, lk = lane >> 4;
  f32x4 z = {0.f, 0.f, 0.f, 0.f};

  // GEMM1: Q = R @ Wq^T, output written per-head-packed into Qp
  for (int nt = wave; nt < 17; nt += 8) {
    int nb = nt * 16;
    f32x4 acc[2] = {z, z};
    gemm_tile<2, QK_PAD, QK_PAD / 32>(Wq + nb * QK_PAD, Rlds, lr, lk, acc);
    int c = nb + lr;
    int h = c / HEAD_DIM, d = c - h * HEAD_DIM;
#pragma unroll
    for (int mt = 0; mt < 2; ++mt)
#pragma unroll
      for (int e = 0; e < 4; ++e) {
        int r = mt * 16 + lk * 4 + e;
        *(short*)(Qp + r * 1024 + h * 128 + ((2 * d) ^ ((r & 7) << 4))) = f2b(acc[mt][e]);
      }
  }
  __syncthreads();

  // GEMM2: Qt[b,h,k] = sum_d Qh[b,h,d] Wkt[h][k][d], scaled
  int h = wave;
  const short* Wh = Wkt + h * 28672;
  for (int nt = 0; nt < 28; ++nt) {
    f32x4 acc[2] = {z, z};
#pragma unroll
    for (int kk = 0; kk < 2; ++kk) {
      short8_t bfrag = *(const short8_t*)(Wh + (nt * 16 + lr) * 64 + kk * 32 + lk * 8);
#pragma unroll
      for (int mt = 0; mt < 2; ++mt) {
        short8_t afrag = *(const short8_t*)(Qp + (mt * 16 + lr) * 1024 + h * 128 +
                                            ((kk * 64 + lk * 16) ^ ((lr & 7) << 4)));
        acc[mt] = __builtin_amdgcn_mfma_f32_16x16x32_bf16(afrag, bfrag, acc[mt], 0, 0, 0);
      }
    }
#pragma unroll
    for (int mt = 0; mt < 2; ++mt)
#pragma unroll
      for (int e = 0; e < 4; ++e)
        Qtg[(size_t)(rb + mt * 16 + lk * 4 + e) * 3584 + h * 448 + nt * 16 + lr] =
            f2b(acc[mt][e] * 0.17149858514250882f);
  }
}

// ---------------- kernel 2: scores + softmax + Yh = P.Z (all-MFMA, static gather) ------
// Yh2 layout: [(h*14+kk2)][b][32 bf16] -> coalesced A-frag reads in out_ln2.
__global__ __launch_bounds__(512) void attn3(const float* __restrict__ nbr_node,
                                             const float* __restrict__ edge_feat,
                                             const float* __restrict__ nbr_time,
                                             const int* __restrict__ nbr_mask,
                                             const short* __restrict__ Qtg,
                                             short* __restrict__ Yh2) {
  __shared__ char Alds[64 * 896];                 // 57,344 B : Z bf16 swizzled
  __shared__ float Spart[2][64][8];               //  4,096 B
  __shared__ char Pb[16 * 128];                   //  2,048 B : P bf16 [16 rows][64 n] swz
  int b = blockIdx.x;
  int t = threadIdx.x;

  stage_rows<64, NODE_DIM, KPAD>(nbr_node + (size_t)b * NBR * NODE_DIM, 0, Alds, t);
  stage_rows<64, EDGE_DIM, KPAD>(edge_feat + (size_t)b * NBR * EDGE_DIM, NODE_DIM, Alds, t);
  stage_rows<64, TIME_DIM, KPAD>(nbr_time + (size_t)b * NBR * TIME_DIM, NODE_DIM + EDGE_DIM,
                                 Alds, t);
  pad_rows<64, KPAD, KEY_DIM>(Alds, t);
  __syncthreads();

  int wave = t >> 6, lane = t & 63, lr = lane & 15, lk = lane >> 4;
  f32x4 z = {0.f, 0.f, 0.f, 0.f};

  // scores: D[h][n] = sum_k Qt[h][k] Z[n][k]; wave = (ntile 0..3, khalf 0..1)
  {
    int nt = wave & 3, kh = wave >> 2;
    f32x4 acc = z;
    const short* qrow = Qtg + (size_t)b * 3584 + (lr & 7) * 448;
    const char* zbase = Alds + (nt * 16 + lr) * 896;
    int swz = (lr & 7) << 4;
#pragma unroll
    for (int k7 = 0; k7 < 7; ++k7) {
      int ke = (kh * 7 + k7) * 32 + lk * 8;        // element offset in [0,448)
      short8_t a = *(const short8_t*)(qrow + ke);
      short8_t bb = *(const short8_t*)(zbase + ((2 * ke) ^ swz));
      acc = __builtin_amdgcn_mfma_f32_16x16x32_bf16(a, bb, acc, 0, 0, 0);
    }
#pragma unroll
    for (int e = 0; e < 4; ++e) {
      int h = lk * 4 + e;
      if (h < 8) Spart[kh][nt * 16 + lr][h] = acc[e];
    }
  }
  __syncthreads();

  // softmax: wave h, lane n (scale folded into Qt); write P as bf16 A-tile
  {
    int h = wave, n = lane;
    float s = Spart[0][n][h] + Spart[1][n][h];
    if (nbr_mask[(size_t)b * NBR + n] == 0) s = -1e10f;
    float m = s;
#pragma unroll
    for (int off = 32; off >= 1; off >>= 1) m = fmaxf(m, __shfl_xor(m, off));
    float e = __expf(s - m);
    float sum = e;
#pragma unroll
    for (int off = 32; off >= 1; off >>= 1) sum += __shfl_xor(sum, off);
    int off2 = (2 * n) ^ ((h & 7) << 4);
    *(short*)(Pb + h * 128 + off2) = f2b(e / sum);
    *(short*)(Pb + (h + 8) * 128 + off2) = 0;     // zero pad rows 8..15
  }
  __syncthreads();

  // Yh[h][k] = sum_n P[h][n] Z[n][k] via MFMA: M=16(h-pad) N=448 K=64.
  // Gather Z columns with STATIC j (n&7 == j since lk*8, kk*32 are mult of 8):
  // every zb element is a compile-time register slot + xor-with-const + imm-offset read.
  for (int vt = wave; vt < 28; vt += 8) {
    int vb = vt * 16;
    f32x4 acc = z;
    int colb = 2 * (vb + lr);                      // byte offset of the k-column
#pragma unroll
    for (int kk = 0; kk < 2; ++kk) {
      short8_t pa = *(const short8_t*)(Pb + lr * 128 +
                                       ((kk * 64 + lk * 16) ^ ((lr & 7) << 4)));
      const char* zb_base = Alds + (kk * 32 + lk * 8) * 896;
      short8_t zb;
#pragma unroll
      for (int j = 0; j < 8; ++j)
        zb[j] = *(const short*)(zb_base + j * 896 + (colb ^ (j << 4)));
      acc = __builtin_amdgcn_mfma_f32_16x16x32_bf16(pa, zb, acc, 0, 0, 0);
    }
    if (lk < 2) {
      int k = vb + lr, kk2 = k >> 5, kp = k & 31;
#pragma unroll
      for (int e = 0; e < 4; ++e) {
        int h = lk * 4 + e;
        Yh2[((size_t)(h * 14 + kk2) * 4096 + b) * 32 + kp] = f2b(acc[e]);
      }
    }
  }
}

// ---------------- kernel 3: O = Yh.Wvh^T ; out = LN(O @ W_O^T + b_O + R) ---------
__global__ __launch_bounds__(512) void out_ln2(const short* __restrict__ Yh2,
                                               const short* __restrict__ Wvh,
                                               const short* __restrict__ Wo,
                                               const float* __restrict__ bO,
                                               const float* __restrict__ node_feat,
                                               const float* __restrict__ time_feat,
                                               const float* __restrict__ gamma,
                                               const float* __restrict__ beta,
                                               float* __restrict__ out) {
  __shared__ char Alds[32 * 640];          // 20,480 B : O tile bf16 swizzled
  __shared__ float X[32 * 276];            // 35,328 B
  int rb = blockIdx.x * 32;
  int t = threadIdx.x;
  int wave = t >> 6, lane = t & 63, lr = lane & 15, lk = lane >> 4;
  pad_rows<32, QK_PAD, OUT_DIM>(Alds, t);  // zero cols 272..319 (disjoint via same-swz xor)
  f32x4 z = {0.f, 0.f, 0.f, 0.f};

  // Phase A: O[r][h*34+cl] = sum_k Yh[r][h][k] Wvh[h][cl][k]; 24 (h,nt) pairs / 8 waves
  for (int p = wave; p < 24; p += 8) {
    int h = p / 3, nt = p - h * 3;
    f32x4 acc[2] = {z, z};
#pragma unroll
    for (int kk = 0; kk < 14; ++kk) {
      short8_t bfrag = *(const short8_t*)(Wvh + h * 21504 + (nt * 16 + lr) * 448 +
                                          kk * 32 + lk * 8);
#pragma unroll
      for (int mt = 0; mt < 2; ++mt) {
        short8_t afrag = *(const short8_t*)(
            Yh2 + ((size_t)(h * 14 + kk) * 4096 + rb + mt * 16 + lr) * 32 + lk * 8);
        acc[mt] = __builtin_amdgcn_mfma_f32_16x16x32_bf16(afrag, bfrag, acc[mt], 0, 0, 0);
      }
    }
    int cl = nt * 16 + lr;
    if (cl < HEAD_DIM) {
      int c = h * HEAD_DIM + cl;
#pragma unroll
      for (int mt = 0; mt < 2; ++mt)
#pragma unroll
        for (int e = 0; e < 4; ++e) {
          int r = mt * 16 + lk * 4 + e;
          *(short*)(Alds + r * 640 + ((2 * c) ^ ((r & 7) << 4))) = f2b(acc[mt][e]);
        }
    }
  }
  __syncthreads();

  // Phase B: proj + bias + residual into X
  for (int nt = wave; nt < 17; nt += 8) {
    int nb = nt * 16;
    f32x4 acc[2] = {z, z};
    gemm_tile<2, QK_PAD, QK_PAD / 32>(Wo + nb * QK_PAD, Alds, lr, lk, acc);
    int c = nb + lr;
    float bo = bO[c];
#pragma unroll
    for (int mt = 0; mt < 2; ++mt)
#pragma unroll
      for (int e = 0; e < 4; ++e) {
        int r = mt * 16 + lk * 4 + e;
        int gr = rb + r;
        float Rv = (c < NODE_DIM) ? node_feat[(size_t)gr * NODE_DIM + c]
                                  : time_feat[(size_t)gr * TIME_DIM + (c - NODE_DIM)];
        X[r * 276 + c] = acc[mt][e] + bo + Rv;
      }
  }
  __syncthreads();

  // LayerNorm: 16 lanes per row
  int row = t >> 4, j = t & 15;
  float s1 = 0.f, s2 = 0.f;
  for (int c = j; c < OUT_DIM; c += 16) {
    float v = X[row * 276 + c];
    s1 += v; s2 += v * v;
  }
#pragma unroll
  for (int off = 8; off >= 1; off >>= 1) {
    s1 += __shfl_xor(s1, off);
    s2 += __shfl_xor(s2, off);
  }
  float mu = s1 * (1.f / OUT_DIM);
  float var = s2 * (1.f / OUT_DIM) - mu * mu;
  float inv = rsqrtf(fmaxf(var, 0.f) + 1e-5f);
  int gr = rb + row;
  for (int c = j; c < OUT_DIM; c += 16) {
    float v = X[row * 276 + c];
    out[(size_t)gr * OUT_DIM + c] = (v - mu) * inv * gamma[c] + beta[c];
  }
}

extern "C" void kernel_launch(void* const* d_in, const int* in_sizes, int n_in,
                              void* d_out, int out_size, void* d_ws, size_t ws_size,
                              hipStream_t stream) {
  const float* node_feat = (const float*)d_in[0];
  const float* time_feat = (const float*)d_in[1];
  const float* edge_feat = (const float*)d_in[2];
  const float* nbr_node  = (const float*)d_in[3];
  const float* nbr_time  = (const float*)d_in[4];
  const int*   nbr_mask  = (const int*)d_in[5];
  const float* W_Q   = (const float*)d_in[6];
  const float* W_KV  = (const float*)d_in[7];
  const float* W_O   = (const float*)d_in[8];
  const float* b_O   = (const float*)d_in[9];
  const float* gamma = (const float*)d_in[10];
  const float* beta  = (const float*)d_in[11];
  float* out = (float*)d_out;
  char* ws = (char*)d_ws;

  // ws layout (requires ~59.9 MB; ws >= 64.8 MB confirmed in round 4):
  short* wq_b = (short*)(ws);                     // 272*320*2   = 174,080
  short* wo_b = (short*)(ws + 174080);            // 174,080 -> 348,160
  short* wvh  = (short*)(ws + 348160);            // 8*48*448*2  = 344,064 -> 692,224
  short* wkt  = (short*)(ws + 692224);            // 8*448*64*2  = 458,752 -> 1,150,976
  short* Qtg  = (short*)(ws + 1150976);           // 4096*3584*2 = 29,360,128 -> 30,511,104
  short* Yh2  = (short*)(ws + 30511104);          // 29,360,128 -> 59,871,232

  convert_w<<<896, 256, 0, stream>>>(W_KV, W_Q, W_O, wq_b, wo_b, wkt, wvh);
  q_qt<<<NROWS / 32, 512, 0, stream>>>(node_feat, time_feat, wq_b, wkt, Qtg);
  attn3<<<NROWS, 512, 0, stream>>>(nbr_node, edge_feat, nbr_time, nbr_mask, Qtg, Yh2);
  out_ln2<<<NROWS / 32, 512, 0, stream>>>(Yh2, wvh, wo_b, b_O, node_feat, time_feat,
                                          gamma, beta, out);
}

// Round 8
// 191.604 us; speedup vs baseline: 4.0376x; 1.1588x over previous
//
#include <hip/hip_runtime.h>
#include <hip/hip_bf16.h>
#include <string.h>

// Problem constants
#define NROWS    4096
#define NBR      64
#define NODE_DIM 172
#define EDGE_DIM 172
#define TIME_DIM 100
#define OUT_DIM  272
#define KEY_DIM  444          // NODE+EDGE+TIME
#define KPAD     448          // KEY_DIM padded; row stride 896B (7*128 -> swizzle-closed)
#define QK_PAD   320          // OUT_DIM padded; row stride 640B (5*128 -> swizzle-closed)
#define N_HEADS  8
#define HEAD_DIM 34

typedef __attribute__((ext_vector_type(8))) short short8_t;  // 8 bf16 in 4 VGPRs
typedef __attribute__((ext_vector_type(4))) float f32x4;

__device__ inline short f2b(float x) {          // fp32 -> bf16 (RNE), scalar one-offs
  unsigned u = __builtin_bit_cast(unsigned, x);
  unsigned r = (u + 0x7fffu + ((u >> 16) & 1u)) >> 16;
  return (short)r;
}

__device__ inline unsigned pk2(float lo, float hi) {  // v_cvt_pk_bf16_f32 via HIP API
  __hip_bfloat162 h = __float22bfloat162_rn(make_float2(lo, hi));
  unsigned u;
  memcpy(&u, &h, 4);                              // bit-identical, reg move after opt
  return u;
}

// Zero cols K0..KP-1 ((KP-K0)*2 must be a multiple of 8).
template<int ROWS, int KP, int K0>
__device__ inline void pad_rows(char* A, int t) {
  constexpr int NC8 = (KP - K0) / 4;         // 8-byte chunks per row
  constexpr int LPR = 512 / ROWS;
  int r = t / LPR;
  int j = t % LPR;
  char* Arow = A + r * (2 * KP);
  int swz = (r & 7) << 4;
  uint2 zz; zz.x = 0; zz.y = 0;
  for (int c8 = j; c8 < NC8; c8 += LPR)
    *(uint2*)(Arow + ((2 * K0 + 8 * c8) ^ swz)) = zz;
}

// One (MT*16)(M) x 16(N) output stripe. B (W) from global L2, A from swizzled LDS.
template<int MT, int KP, int NKK>
__device__ inline void gemm_tile(const short* __restrict__ Wrow, const char* A,
                                 int lr, int lk, f32x4* acc) {
#pragma unroll
  for (int kk = 0; kk < NKK; ++kk) {
    short8_t bfrag = *(const short8_t*)(Wrow + lr * KP + kk * 32 + lk * 8);
#pragma unroll
    for (int mt = 0; mt < MT; ++mt) {
      short8_t afrag = *(const short8_t*)(A + (mt * 16 + lr) * (2 * KP) +
                                          ((kk * 64 + lk * 16) ^ ((lr & 7) << 4)));
      acc[mt] = __builtin_amdgcn_mfma_f32_16x16x32_bf16(afrag, bfrag, acc[mt], 0, 0, 0);
    }
  }
}

// ---------------- kernel 0: weight conversion fp32 -> padded bf16 ----------------
__global__ void convert_w(const float* __restrict__ Wkv, const float* __restrict__ Wq,
                          const float* __restrict__ Wo, short* __restrict__ wq_b,
                          short* __restrict__ wo_b, short* __restrict__ wkt,
                          short* __restrict__ wvh) {
  int i = blockIdx.x * 256 + threadIdx.x;
  if (i < OUT_DIM * QK_PAD) {
    int r = i / QK_PAD, c = i - r * QK_PAD;
    wq_b[i] = (c < OUT_DIM) ? f2b(Wq[r * OUT_DIM + c]) : (short)0;
    wo_b[i] = (c < OUT_DIM) ? f2b(Wo[r * OUT_DIM + c]) : (short)0;
  }
  // Wkt[h][n=448][d=64] = W_KV[h*34+d][n]  (d>=34 or n>=444 -> 0)
  if (i < N_HEADS * 448 * 64) {
    int h = i / 28672;
    int rem = i - h * 28672;
    int n = rem >> 6, d = rem & 63;
    wkt[i] = (n < KEY_DIM && d < HEAD_DIM) ? f2b(Wkv[(h * HEAD_DIM + d) * KEY_DIM + n])
                                           : (short)0;
  }
  // Wvh[h][c'=48][k=448] = W_KV[272 + h*34 + c'][k]  (c'>=34 or k>=444 -> 0)
  if (i < N_HEADS * 48 * 448) {
    int h = i / 21504;
    int rem = i - h * 21504;
    int cp = rem / 448, k = rem - cp * 448;
    wvh[i] = (cp < HEAD_DIM && k < KEY_DIM)
                 ? f2b(Wkv[(OUT_DIM + h * HEAD_DIM + cp) * KEY_DIM + k])
                 : (short)0;
  }
}

// ---------------- kernel 1 (fused): Q = R@Wq^T (LDS) ; Qt = (1/sqrt34) Qh@Wk ----------
__global__ __launch_bounds__(512) void q_qt(const float* __restrict__ node_feat,
                                            const float* __restrict__ time_feat,
                                            const short* __restrict__ Wq,
                                            const short* __restrict__ Wkt,
                                            short* __restrict__ Qtg) {
  __shared__ char Rlds[32 * 640];    // 20,480 B : R tile bf16 swizzled
  __shared__ char Qp[32 * 1024];     // 32,768 B : Q per-head packed [row][h*128B + 2d]
  int rb = blockIdx.x * 32, t = threadIdx.x;

  // Batched staging: uniform trip counts via clamped indices -> all loads issue together.
  {
    int r = t >> 4, j = t & 15;      // 16 lanes per row
    const float4* pn = (const float4*)(node_feat + (size_t)(rb + r) * NODE_DIM);
    const float4* pt = (const float4*)(time_feat + (size_t)(rb + r) * TIME_DIM);
    float4 vn[3], vt4[2];
    int in_[3], it_[2];
#pragma unroll
    for (int i = 0; i < 3; ++i) { int f = j + 16 * i; in_[i] = f > 42 ? 42 : f; vn[i] = pn[in_[i]]; }
#pragma unroll
    for (int i = 0; i < 2; ++i) { int f = j + 16 * i; it_[i] = f > 24 ? 24 : f; vt4[i] = pt[it_[i]]; }
    char* Arow = Rlds + r * 640;
    int swz = (r & 7) << 4;
#pragma unroll
    for (int i = 0; i < 3; ++i) {
      uint2 w; w.x = pk2(vn[i].x, vn[i].y); w.y = pk2(vn[i].z, vn[i].w);
      *(uint2*)(Arow + ((8 * in_[i]) ^ swz)) = w;
    }
#pragma unroll
    for (int i = 0; i < 2; ++i) {
      uint2 w; w.x = pk2(vt4[i].x, vt4[i].y); w.y = pk2(vt4[i].z, vt4[i].w);
      *(uint2*)(Arow + ((344 + 8 * it_[i]) ^ swz)) = w;
    }
    if (j < 12) { uint2 zz; zz.x = 0; zz.y = 0; *(uint2*)(Arow + ((544 + 8 * j) ^ swz)) = zz; }
  }
  {
    uint4 zz; zz.x = 0; zz.y = 0; zz.z = 0; zz.w = 0;
    for (int i = t; i < 2048; i += 512) ((uint4*)Qp)[i] = zz;
  }
  __syncthreads();
  int wave = t >> 6, lane = t & 63, lr = lane & 15, lk = lane >> 4;
  f32x4 z = {0.f, 0.f, 0.f, 0.f};

  // GEMM1: Q = R @ Wq^T, output written per-head-packed into Qp
  for (int nt = wave; nt < 17; nt += 8) {
    int nb = nt * 16;
    f32x4 acc[2] = {z, z};
    gemm_tile<2, QK_PAD, QK_PAD / 32>(Wq + nb * QK_PAD, Rlds, lr, lk, acc);
    int c = nb + lr;
    int h = c / HEAD_DIM, d = c - h * HEAD_DIM;
#pragma unroll
    for (int mt = 0; mt < 2; ++mt)
#pragma unroll
      for (int e = 0; e < 4; ++e) {
        int r = mt * 16 + lk * 4 + e;
        *(short*)(Qp + r * 1024 + h * 128 + ((2 * d) ^ ((r & 7) << 4))) = f2b(acc[mt][e]);
      }
  }
  __syncthreads();

  // GEMM2: Qt[b,h,k] = sum_d Qh[b,h,d] Wkt[h][k][d], scaled
  int h = wave;
  const short* Wh = Wkt + h * 28672;
  for (int nt = 0; nt < 28; ++nt) {
    f32x4 acc[2] = {z, z};
#pragma unroll
    for (int kk = 0; kk < 2; ++kk) {
      short8_t bfrag = *(const short8_t*)(Wh + (nt * 16 + lr) * 64 + kk * 32 + lk * 8);
#pragma unroll
      for (int mt = 0; mt < 2; ++mt) {
        short8_t afrag = *(const short8_t*)(Qp + (mt * 16 + lr) * 1024 + h * 128 +
                                            ((kk * 64 + lk * 16) ^ ((lr & 7) << 4)));
        acc[mt] = __builtin_amdgcn_mfma_f32_16x16x32_bf16(afrag, bfrag, acc[mt], 0, 0, 0);
      }
    }
#pragma unroll
    for (int mt = 0; mt < 2; ++mt)
#pragma unroll
      for (int e = 0; e < 4; ++e)
        Qtg[(size_t)(rb + mt * 16 + lk * 4 + e) * 3584 + h * 448 + nt * 16 + lr] =
            f2b(acc[mt][e] * 0.17149858514250882f);
  }
}

// ---------------- kernel 2: scores + softmax + Yh = P.Z (all-MFMA, batched stage) ------
// Yh2 layout: [(h*14+kk2)][b][32 bf16] -> coalesced A-frag reads in out_ln2.
__global__ __launch_bounds__(512) void attn3(const float* __restrict__ nbr_node,
                                             const float* __restrict__ edge_feat,
                                             const float* __restrict__ nbr_time,
                                             const int* __restrict__ nbr_mask,
                                             const short* __restrict__ Qtg,
                                             short* __restrict__ Yh2) {
  __shared__ char Alds[64 * 896];                 // 57,344 B : Z bf16 swizzled
  __shared__ float Spart[2][64][8];               //  4,096 B
  __shared__ char Pb[16 * 128];                   //  2,048 B : P bf16 [16 rows][64 n] swz
  int b = blockIdx.x;
  int t = threadIdx.x;

  // Batched staging: 8 lanes/row; clamped uniform trip counts -> 16 loads issue together,
  // one wait, then convert+write. (Clamped lanes re-load/re-write the row's last float4 —
  // same address, same value, benign.)
  {
    int r = t >> 3, j = t & 7;
    const float4* pn = (const float4*)(nbr_node + (size_t)b * NBR * NODE_DIM) + (size_t)r * 43;
    const float4* pe = (const float4*)(edge_feat + (size_t)b * NBR * EDGE_DIM) + (size_t)r * 43;
    const float4* pt = (const float4*)(nbr_time + (size_t)b * NBR * TIME_DIM) + (size_t)r * 25;
    float4 vn[6], ve[6], vt4[4];
    int in_[6], it_[4];
#pragma unroll
    for (int i = 0; i < 6; ++i) { int f = j + 8 * i; in_[i] = f > 42 ? 42 : f; vn[i] = pn[in_[i]]; }
#pragma unroll
    for (int i = 0; i < 6; ++i) { ve[i] = pe[in_[i]]; }
#pragma unroll
    for (int i = 0; i < 4; ++i) { int f = j + 8 * i; it_[i] = f > 24 ? 24 : f; vt4[i] = pt[it_[i]]; }
    char* Arow = Alds + r * 896;
    int swz = (r & 7) << 4;
#pragma unroll
    for (int i = 0; i < 6; ++i) {
      uint2 w; w.x = pk2(vn[i].x, vn[i].y); w.y = pk2(vn[i].z, vn[i].w);
      *(uint2*)(Arow + ((8 * in_[i]) ^ swz)) = w;
    }
#pragma unroll
    for (int i = 0; i < 6; ++i) {
      uint2 w; w.x = pk2(ve[i].x, ve[i].y); w.y = pk2(ve[i].z, ve[i].w);
      *(uint2*)(Arow + ((344 + 8 * in_[i]) ^ swz)) = w;
    }
#pragma unroll
    for (int i = 0; i < 4; ++i) {
      uint2 w; w.x = pk2(vt4[i].x, vt4[i].y); w.y = pk2(vt4[i].z, vt4[i].w);
      *(uint2*)(Arow + ((688 + 8 * it_[i]) ^ swz)) = w;
    }
    if (j == 0) { uint2 zz; zz.x = 0; zz.y = 0; *(uint2*)(Arow + (888 ^ swz)) = zz; }
  }
  __syncthreads();

  int wave = t >> 6, lane = t & 63, lr = lane & 15, lk = lane >> 4;
  f32x4 z = {0.f, 0.f, 0.f, 0.f};

  // scores: D[h][n] = sum_k Qt[h][k] Z[n][k]; wave = (ntile 0..3, khalf 0..1)
  {
    int nt = wave & 3, kh = wave >> 2;
    f32x4 acc = z;
    const short* qrow = Qtg + (size_t)b * 3584 + (lr & 7) * 448;
    const char* zbase = Alds + (nt * 16 + lr) * 896;
    int swz = (lr & 7) << 4;
#pragma unroll
    for (int k7 = 0; k7 < 7; ++k7) {
      int ke = (kh * 7 + k7) * 32 + lk * 8;        // element offset in [0,448)
      short8_t a = *(const short8_t*)(qrow + ke);
      short8_t bb = *(const short8_t*)(zbase + ((2 * ke) ^ swz));
      acc = __builtin_amdgcn_mfma_f32_16x16x32_bf16(a, bb, acc, 0, 0, 0);
    }
#pragma unroll
    for (int e = 0; e < 4; ++e) {
      int h = lk * 4 + e;
      if (h < 8) Spart[kh][nt * 16 + lr][h] = acc[e];
    }
  }
  __syncthreads();

  // softmax: wave h, lane n (scale folded into Qt); write P as bf16 A-tile
  {
    int h = wave, n = lane;
    float s = Spart[0][n][h] + Spart[1][n][h];
    if (nbr_mask[(size_t)b * NBR + n] == 0) s = -1e10f;
    float m = s;
#pragma unroll
    for (int off = 32; off >= 1; off >>= 1) m = fmaxf(m, __shfl_xor(m, off));
    float e = __expf(s - m);
    float sum = e;
#pragma unroll
    for (int off = 32; off >= 1; off >>= 1) sum += __shfl_xor(sum, off);
    int off2 = (2 * n) ^ ((h & 7) << 4);
    *(short*)(Pb + h * 128 + off2) = f2b(e / sum);
    *(short*)(Pb + (h + 8) * 128 + off2) = 0;     // zero pad rows 8..15
  }
  __syncthreads();

  // Yh[h][k] = sum_n P[h][n] Z[n][k] via MFMA: M=16(h-pad) N=448 K=64.
  // Static-j gather: compile-time register slots + xor-with-const + imm-offset reads.
  for (int vt = wave; vt < 28; vt += 8) {
    int vb = vt * 16;
    f32x4 acc = z;
    int colb = 2 * (vb + lr);                      // byte offset of the k-column
#pragma unroll
    for (int kk = 0; kk < 2; ++kk) {
      short8_t pa = *(const short8_t*)(Pb + lr * 128 +
                                       ((kk * 64 + lk * 16) ^ ((lr & 7) << 4)));
      const char* zb_base = Alds + (kk * 32 + lk * 8) * 896;
      short8_t zb;
#pragma unroll
      for (int j = 0; j < 8; ++j)
        zb[j] = *(const short*)(zb_base + j * 896 + (colb ^ (j << 4)));
      acc = __builtin_amdgcn_mfma_f32_16x16x32_bf16(pa, zb, acc, 0, 0, 0);
    }
    if (lk < 2) {
      int k = vb + lr, kk2 = k >> 5, kp = k & 31;
#pragma unroll
      for (int e = 0; e < 4; ++e) {
        int h = lk * 4 + e;
        Yh2[((size_t)(h * 14 + kk2) * 4096 + b) * 32 + kp] = f2b(acc[e]);
      }
    }
  }
}

// ---------------- kernel 3: O = Yh.Wvh^T ; out = LN(O @ W_O^T + b_O + R) ---------
__global__ __launch_bounds__(512) void out_ln2(const short* __restrict__ Yh2,
                                               const short* __restrict__ Wvh,
                                               const short* __restrict__ Wo,
                                               const float* __restrict__ bO,
                                               const float* __restrict__ node_feat,
                                               const float* __restrict__ time_feat,
                                               const float* __restrict__ gamma,
                                               const float* __restrict__ beta,
                                               float* __restrict__ out) {
  __shared__ char Alds[32 * 640];          // 20,480 B : O tile bf16 swizzled
  __shared__ float X[32 * 276];            // 35,328 B
  int rb = blockIdx.x * 32;
  int t = threadIdx.x;
  int wave = t >> 6, lane = t & 63, lr = lane & 15, lk = lane >> 4;
  pad_rows<32, QK_PAD, OUT_DIM>(Alds, t);  // zero cols 272..319 (disjoint via same-swz xor)
  f32x4 z = {0.f, 0.f, 0.f, 0.f};

  // Phase A: O[r][h*34+cl] = sum_k Yh[r][h][k] Wvh[h][cl][k]; 24 (h,nt) pairs / 8 waves
  for (int p = wave; p < 24; p += 8) {
    int h = p / 3, nt = p - h * 3;
    f32x4 acc[2] = {z, z};
#pragma unroll
    for (int kk = 0; kk < 14; ++kk) {
      short8_t bfrag = *(const short8_t*)(Wvh + h * 21504 + (nt * 16 + lr) * 448 +
                                          kk * 32 + lk * 8);
#pragma unroll
      for (int mt = 0; mt < 2; ++mt) {
        short8_t afrag = *(const short8_t*)(
            Yh2 + ((size_t)(h * 14 + kk) * 4096 + rb + mt * 16 + lr) * 32 + lk * 8);
        acc[mt] = __builtin_amdgcn_mfma_f32_16x16x32_bf16(afrag, bfrag, acc[mt], 0, 0, 0);
      }
    }
    int cl = nt * 16 + lr;
    if (cl < HEAD_DIM) {
      int c = h * HEAD_DIM + cl;
#pragma unroll
      for (int mt = 0; mt < 2; ++mt)
#pragma unroll
        for (int e = 0; e < 4; ++e) {
          int r = mt * 16 + lk * 4 + e;
          *(short*)(Alds + r * 640 + ((2 * c) ^ ((r & 7) << 4))) = f2b(acc[mt][e]);
        }
    }
  }
  __syncthreads();

  // Phase B: proj + bias + residual into X
  for (int nt = wave; nt < 17; nt += 8) {
    int nb = nt * 16;
    f32x4 acc[2] = {z, z};
    gemm_tile<2, QK_PAD, QK_PAD / 32>(Wo + nb * QK_PAD, Alds, lr, lk, acc);
    int c = nb + lr;
    float bo = bO[c];
#pragma unroll
    for (int mt = 0; mt < 2; ++mt)
#pragma unroll
      for (int e = 0; e < 4; ++e) {
        int r = mt * 16 + lk * 4 + e;
        int gr = rb + r;
        float Rv = (c < NODE_DIM) ? node_feat[(size_t)gr * NODE_DIM + c]
                                  : time_feat[(size_t)gr * TIME_DIM + (c - NODE_DIM)];
        X[r * 276 + c] = acc[mt][e] + bo + Rv;
      }
  }
  __syncthreads();

  // LayerNorm: 16 lanes per row
  int row = t >> 4, j = t & 15;
  float s1 = 0.f, s2 = 0.f;
  for (int c = j; c < OUT_DIM; c += 16) {
    float v = X[row * 276 + c];
    s1 += v; s2 += v * v;
  }
#pragma unroll
  for (int off = 8; off >= 1; off >>= 1) {
    s1 += __shfl_xor(s1, off);
    s2 += __shfl_xor(s2, off);
  }
  float mu = s1 * (1.f / OUT_DIM);
  float var = s2 * (1.f / OUT_DIM) - mu * mu;
  float inv = rsqrtf(fmaxf(var, 0.f) + 1e-5f);
  int gr = rb + row;
  for (int c = j; c < OUT_DIM; c += 16) {
    float v = X[row * 276 + c];
    out[(size_t)gr * OUT_DIM + c] = (v - mu) * inv * gamma[c] + beta[c];
  }
}

extern "C" void kernel_launch(void* const* d_in, const int* in_sizes, int n_in,
                              void* d_out, int out_size, void* d_ws, size_t ws_size,
                              hipStream_t stream) {
  const float* node_feat = (const float*)d_in[0];
  const float* time_feat = (const float*)d_in[1];
  const float* edge_feat = (const float*)d_in[2];
  const float* nbr_node  = (const float*)d_in[3];
  const float* nbr_time  = (const float*)d_in[4];
  const int*   nbr_mask  = (const int*)d_in[5];
  const float* W_Q   = (const float*)d_in[6];
  const float* W_KV  = (const float*)d_in[7];
  const float* W_O   = (const float*)d_in[8];
  const float* b_O   = (const float*)d_in[9];
  const float* gamma = (const float*)d_in[10];
  const float* beta  = (const float*)d_in[11];
  float* out = (float*)d_out;
  char* ws = (char*)d_ws;

  // ws layout (requires ~59.9 MB; ws >= 64.8 MB confirmed in round 4):
  short* wq_b = (short*)(ws);                     // 272*320*2   = 174,080
  short* wo_b = (short*)(ws + 174080);            // 174,080 -> 348,160
  short* wvh  = (short*)(ws + 348160);            // 8*48*448*2  = 344,064 -> 692,224
  short* wkt  = (short*)(ws + 692224);            // 8*448*64*2  = 458,752 -> 1,150,976
  short* Qtg  = (short*)(ws + 1150976);           // 4096*3584*2 = 29,360,128 -> 30,511,104
  short* Yh2  = (short*)(ws + 30511104);          // 29,360,128 -> 59,871,232

  convert_w<<<896, 256, 0, stream>>>(W_KV, W_Q, W_O, wq_b, wo_b, wkt, wvh);
  q_qt<<<NROWS / 32, 512, 0, stream>>>(node_feat, time_feat, wq_b, wkt, Qtg);
  attn3<<<NROWS, 512, 0, stream>>>(nbr_node, edge_feat, nbr_time, nbr_mask, Qtg, Yh2);
  out_ln2<<<NROWS / 32, 512, 0, stream>>>(Yh2, wvh, wo_b, b_O, node_feat, time_feat,
                                          gamma, beta, out);
}